// Round 17
// baseline (891.286 us; speedup 1.0000x reference)
//
#include <hip/hip_runtime.h>
#include <math.h>

#define HID 256
#define EBUY 200000
#define NNODE 30000
#define MPD 30208
static const size_t S   = (size_t)NNODE * HID;
static const size_t SP  = (size_t)MPD * HID;
static const size_t SP2 = (size_t)MPD * 512;

typedef __attribute__((ext_vector_type(8))) short  short8;
typedef __attribute__((ext_vector_type(4))) float  f32x4;

#define OFF_TASTE 0
#define OFF_INT   196608
#define OFF_IMGU  204800
#define OFF_IMGV  237568
#define OFF_USER  253952
#define OFF_ITEM  270336
#define OFF_OUTW  286720
#define WENC_TOT  548864

__device__ __forceinline__ float gelu_f(float x) {
    return 0.5f * x * (1.0f + erff(x * 0.70710678118654752f));
}
__device__ __forceinline__ unsigned short f2bf(float f) {
    unsigned u = __float_as_uint(f);
    u = (u + 0x7FFFu + ((u >> 16) & 1u)) >> 16;
    return (unsigned short)u;
}
__device__ __forceinline__ float b2f(unsigned short us) {
    return __uint_as_float((unsigned)us << 16);
}
__device__ __forceinline__ void gl_lds16(const unsigned short* g, unsigned short* l) {
    __builtin_amdgcn_global_load_lds(
        (const __attribute__((address_space(1))) unsigned int*)g,
        (__attribute__((address_space(3))) unsigned int*)l, 16, 0, 0);
}
__device__ __forceinline__ int xcd_swz(int bid, int nwg) {
    int q = nwg >> 3, r = nwg & 7;
    int xc = bid & 7, i = bid >> 3;
    int base = (xc < r) ? xc * (q + 1) : r * (q + 1) + (xc - r) * q;
    return base + i;
}

// ---------------- conversions / weight prep ----------------
__global__ void conv_pad(const float* __restrict__ in, unsigned short* __restrict__ o,
                         int M, int K, int Kpad)
{
    int i = blockIdx.x * 256 + threadIdx.x;
    if (i >= M * Kpad) return;
    int r = i / Kpad, k = i % Kpad;
    o[i] = (k < K) ? f2bf(in[(size_t)r * K + k]) : (unsigned short)0;
}

__global__ void conv2bf(const float* __restrict__ a, int na4, unsigned short* __restrict__ oa,
                        const float* __restrict__ b, int nb4, unsigned short* __restrict__ ob)
{
    int total = na4 + nb4;
    for (int i = blockIdx.x * 256 + threadIdx.x; i < total; i += gridDim.x * 256) {
        if (i < na4) {
            float4 v = ((const float4*)a)[i];
            ushort4 u = {f2bf(v.x), f2bf(v.y), f2bf(v.z), f2bf(v.w)};
            ((ushort4*)oa)[i] = u;
        } else {
            int j = i - na4;
            float4 v = ((const float4*)b)[j];
            ushort4 u = {f2bf(v.x), f2bf(v.y), f2bf(v.z), f2bf(v.w)};
            ((ushort4*)ob)[j] = u;
        }
    }
}

__global__ void wtconv_all(const float* __restrict__ taste_W, const float* __restrict__ intent_W,
                           const float* __restrict__ img_U, const float* __restrict__ img_V,
                           const float* __restrict__ user_W, const float* __restrict__ item_W,
                           const float* __restrict__ out_W, unsigned short* __restrict__ WENC)
{
    int i = blockIdx.x * 256 + threadIdx.x;
    if (i >= WENC_TOT) return;
    const float* W; int K, N, Kpad, idx;
    if (i < OFF_INT)        { W = taste_W;  K = 768; N = 256; Kpad = 768; idx = i - OFF_TASTE; }
    else if (i < OFF_IMGU)  { W = intent_W; K = 20;  N = 256; Kpad = 32;  idx = i - OFF_INT; }
    else if (i < OFF_IMGV)  { W = img_U;    K = 512; N = 64;  Kpad = 512; idx = i - OFF_IMGU; }
    else if (i < OFF_USER)  { W = img_V;    K = 64;  N = 256; Kpad = 64;  idx = i - OFF_IMGV; }
    else if (i < OFF_ITEM)  { W = user_W;   K = 64;  N = 256; Kpad = 64;  idx = i - OFF_USER; }
    else if (i < OFF_OUTW)  { W = item_W;   K = 64;  N = 256; Kpad = 64;  idx = i - OFF_ITEM; }
    else {
        int k = (i - OFF_OUTW) >> 16;
        int l = k >> 1, d = k & 1;
        W = out_W + (size_t)(l * 5 + d) * 65536;
        K = 256; N = 256; Kpad = 256; idx = (i - OFF_OUTW) & 65535;
    }
    int n = idx / Kpad, kk = idx % Kpad;
    WENC[i] = (kk < K) ? f2bf(W[(size_t)kk * N + n]) : (unsigned short)0;
}

__global__ void build_kqv(const float* __restrict__ kqv_W, const float* __restrict__ kqv_b,
                          const float* __restrict__ k_rel, const float* __restrict__ v_rel,
                          unsigned short* __restrict__ WALL, float* __restrict__ bALL)
{
    int s = blockIdx.y;
    int l = s / 5, t = s % 5;
    static const int es[5] = {3, 4, 0, 1, 2};
    int e = es[t];
    int tid = blockIdx.x * 256 + threadIdx.x;
    if (tid >= 257 * 768) return;
    int r = tid / 768, c = tid % 768;
    int cb = c >> 8, cc = c & 255;
    int h = cc >> 6, dd = cc & 63;
    const float* W = kqv_W + (size_t)s * 196608;
    const float* bv = kqv_b + (size_t)s * 768;
    const float* Wrow = (r < 256) ? (W + (size_t)r * 768) : bv;
    if (cb == 1) {
        if (t >= 2) return;
        float outv = Wrow[256 + cc];
        if (r < 256) WALL[(size_t)s * 196608 + (size_t)(512 + cc) * 256 + r] = f2bf(outv);
        else         bALL[s * 768 + 512 + cc] = outv;
        return;
    }
    const float* R = ((cb == 0) ? k_rel : v_rel) + (size_t)(l * 5 + e) * 16384 + (size_t)h * 4096;
    int sb = (cb == 0) ? 0 : 512;
    float sum = 0.f;
    #pragma unroll 8
    for (int d = 0; d < 64; ++d)
        sum += Wrow[sb + h * 64 + d] * R[d * 64 + dd];
    int col = (cb == 0) ? cc : 256 + cc;
    if (r < 256) WALL[(size_t)s * 196608 + (size_t)col * 256 + r] = f2bf(sum);
    else         bALL[s * 768 + col] = sum;
}

// ---------------- unified 128x128 bf16 MFMA GEMM (BK=32, depth-1) ----------------
template<int AF32, int GATH2, int EPI>
__launch_bounds__(256)
__global__ void gemm_mfma(const void* __restrict__ Ap, const void* __restrict__ Ap2,
                          const int* __restrict__ g1, const int* __restrict__ g2,
                          const unsigned short* __restrict__ BT0,
                          const float* __restrict__ bias0, const float* __restrict__ bias1,
                          float* __restrict__ D0, unsigned short* __restrict__ Db,
                          int M, int N, int K)
{
    __shared__ union {
        unsigned short AB[4][4096];
        unsigned short O[16384];
    } sm;
    const int tid = threadIdx.x;
    const int gx = gridDim.x;
    int bid = xcd_swz(blockIdx.y * gx + blockIdx.x, gx * gridDim.y);
    const int bx = bid % gx, by = bid / gx;
    const int row0 = by * 128, col0 = bx * 128;
    const int wid = tid >> 6, lane = tid & 63;
    const int wr = wid >> 1, wc = wid & 1;
    const int l16 = lane & 15, kg = lane >> 4;
    const int tt = GATH2 ? (by / 236) : 0;

    const unsigned short* BT = BT0;
    if (GATH2 && tt) BT = BT0 + 16384;
    const float* bias = bias0;
    if (GATH2) bias = tt ? bias1 : bias0;

    f32x4 acc[4][4];
    const f32x4 zero = {0.f, 0.f, 0.f, 0.f};
    #pragma unroll
    for (int i = 0; i < 4; ++i)
        #pragma unroll
        for (int j = 0; j < 4; ++j) acc[i][j] = zero;

    const int lrow = lane >> 2, lchk = lane & 3;
    const int gsw = (lchk ^ ((lrow >> 1) & 3)) * 8;
    int cB0 = min(col0 + wid * 32 + lrow, N - 1);
    int cB1 = min(col0 + wid * 32 + 16 + lrow, N - 1);
    const unsigned short* Bp0 = BT + (size_t)cB0 * K + gsw;
    const unsigned short* Bp1 = BT + (size_t)cB1 * K + gsw;
    const int ofs0 = wid * 1024, ofs1 = wid * 1024 + 512;

    const unsigned short* Ap0b = nullptr; const unsigned short* Ap1b = nullptr;
    const float* Af0 = nullptr; const float* Af1 = nullptr;
    const int rA0 = tid >> 2, rA1 = (tid >> 2) + 64;
    const int q0 = tid & 3;
    const int wsw = (q0 ^ ((rA0 >> 1) & 3)) * 8;
    if (GATH2) {
        int lr0 = row0 + rA0 - tt * MPD; if (lr0 >= NNODE) lr0 = NNODE - 1;
        int lr1 = row0 + rA1 - tt * MPD; if (lr1 >= NNODE) lr1 = NNODE - 1;
        const int* gA = tt ? g2 : g1;
        const float* Abase = tt ? (const float*)Ap2 : (const float*)Ap;
        Af0 = Abase + (size_t)gA[lr0] * K;
        Af1 = Abase + (size_t)gA[lr1] * K;
    } else if (AF32) {
        Af0 = (const float*)Ap + (size_t)min(row0 + rA0, M - 1) * K;
        Af1 = (const float*)Ap + (size_t)min(row0 + rA1, M - 1) * K;
    } else {
        int rr0 = min(row0 + wid * 32 + lrow, M - 1);
        int rr1 = min(row0 + wid * 32 + 16 + lrow, M - 1);
        Ap0b = (const unsigned short*)Ap + (size_t)rr0 * K + gsw;
        Ap1b = (const unsigned short*)Ap + (size_t)rr1 * K + gsw;
    }

    const int nt = K >> 5;
    const int rsw = ((l16 >> 1) & 3);

    #define STAGE_F32(c, k0) do { \
        float4 x0 = *(const float4*)&Af0[(k0) + q0 * 8]; \
        float4 x1 = *(const float4*)&Af0[(k0) + q0 * 8 + 4]; \
        float4 y0 = *(const float4*)&Af1[(k0) + q0 * 8]; \
        float4 y1 = *(const float4*)&Af1[(k0) + q0 * 8 + 4]; \
        ushort4 u0 = {f2bf(x0.x), f2bf(x0.y), f2bf(x0.z), f2bf(x0.w)}; \
        ushort4 u1 = {f2bf(x1.x), f2bf(x1.y), f2bf(x1.z), f2bf(x1.w)}; \
        ushort4 w0 = {f2bf(y0.x), f2bf(y0.y), f2bf(y0.z), f2bf(y0.w)}; \
        ushort4 w1 = {f2bf(y1.x), f2bf(y1.y), f2bf(y1.z), f2bf(y1.w)}; \
        *(ushort4*)&sm.AB[c][rA0 * 32 + wsw]     = u0; \
        *(ushort4*)&sm.AB[c][rA0 * 32 + wsw + 4] = u1; \
        *(ushort4*)&sm.AB[c][rA1 * 32 + wsw]     = w0; \
        *(ushort4*)&sm.AB[c][rA1 * 32 + wsw + 4] = w1; \
        gl_lds16(Bp0 + (k0), &sm.AB[2 + (c)][ofs0]); \
        gl_lds16(Bp1 + (k0), &sm.AB[2 + (c)][ofs1]); \
    } while (0)

    #define STAGE_A(c, k0) do { \
        gl_lds16(Ap0b + (k0), &sm.AB[c][ofs0]); \
        gl_lds16(Ap1b + (k0), &sm.AB[c][ofs1]); \
        gl_lds16(Bp0 + (k0), &sm.AB[2 + (c)][ofs0]); \
        gl_lds16(Bp1 + (k0), &sm.AB[2 + (c)][ofs1]); \
    } while (0)

    #define LOADFRAG(c) do { \
        _Pragma("unroll") \
        for (int i = 0; i < 4; ++i) { \
            af[i]  = *(const short8*)&sm.AB[c][(wr * 64 + i * 16 + l16) * 32 + (kg ^ rsw) * 8]; \
            bfr[i] = *(const short8*)&sm.AB[2 + (c)][(wc * 64 + i * 16 + l16) * 32 + (kg ^ rsw) * 8]; \
        } \
    } while (0)

    #define MMAS() do { \
        _Pragma("unroll") \
        for (int i = 0; i < 4; ++i) \
            _Pragma("unroll") \
            for (int j = 0; j < 4; ++j) \
                acc[i][j] = __builtin_amdgcn_mfma_f32_16x16x32_bf16(af[i], bfr[j], acc[i][j], 0, 0, 0); \
    } while (0)

    if (AF32 || GATH2) {
        STAGE_F32(0, 0);
        __syncthreads();
        int cur = 0;
        for (int s = 0; s < nt; ++s) {
            if (s + 1 < nt) STAGE_F32(cur ^ 1, (s + 1) * 32);
            short8 af[4], bfr[4];
            LOADFRAG(cur);
            MMAS();
            __syncthreads();
            cur ^= 1;
        }
    } else {
        STAGE_A(0, 0);
        int cur = 0;
        for (int s = 0; s < nt; ++s) {
            if (s + 1 < nt) {
                STAGE_A(cur ^ 1, (s + 1) * 32);
                asm volatile("s_waitcnt vmcnt(4)" ::: "memory");
            } else {
                asm volatile("s_waitcnt vmcnt(0)" ::: "memory");
            }
            __builtin_amdgcn_s_barrier();
            asm volatile("" ::: "memory");
            short8 af[4], bfr[4];
            LOADFRAG(cur);
            __builtin_amdgcn_s_setprio(1);
            MMAS();
            __builtin_amdgcn_s_setprio(0);
            __builtin_amdgcn_s_barrier();
            asm volatile("" ::: "memory");
            cur ^= 1;
        }
    }
    #undef STAGE_F32
    #undef STAGE_A
    #undef LOADFRAG
    #undef MMAS

    #pragma unroll
    for (int j = 0; j < 4; ++j) {
        int lc = wc * 64 + j * 16 + l16;
        int cc = col0 + lc;
        float bv = (bias && cc < N) ? bias[cc] : 0.f;
        #pragma unroll
        for (int i = 0; i < 4; ++i) {
            #pragma unroll
            for (int r = 0; r < 4; ++r) {
                int lr = wr * 64 + i * 16 + kg * 4 + r;
                int rr = row0 + lr;
                float v = acc[i][j][r] + bv;
                if (EPI == 0) {
                    if (D0 && cc < N && rr < M) D0[(size_t)rr * N + cc] = v;
                    sm.O[lr * 128 + ((((lc >> 3) ^ (lr & 7)) << 3) | (lc & 7))] = f2bf(v);
                } else if (EPI == 6) {
                    D0[(size_t)rr * 256 + cc] = v;
                }
            }
        }
    }
    if (EPI == 0) {
        __syncthreads();
        int nloc = N - col0; if (nloc > 128) nloc = 128;
        if (nloc >= 128) {
            int lr = tid >> 1, half = tid & 1;
            int rr = row0 + lr;
            if (rr < M) {
                uint4* dst = (uint4*)&Db[(size_t)rr * N + col0 + half * 64];
                #pragma unroll
                for (int c = 0; c < 8; ++c) {
                    int ch = half * 8 + c;
                    dst[c] = *(const uint4*)&sm.O[lr * 128 + ((ch ^ (lr & 7)) << 3)];
                }
            }
        } else {
            if (tid < 128) {
                int lr = tid, rr = row0 + lr;
                if (rr < M) {
                    uint4* dst = (uint4*)&Db[(size_t)rr * N + col0];
                    #pragma unroll
                    for (int c = 0; c < 8; ++c)
                        dst[c] = *(const uint4*)&sm.O[lr * 128 + ((c ^ (lr & 7)) << 3)];
                }
            }
        }
    }
}

// ---------------- merged encoder GEMM: taste(K=768) | intent(K=32) | imgU(K=512,N=64) ----------------
__launch_bounds__(256)
__global__ void gemm_enc(const unsigned short* __restrict__ TFB,
                         const unsigned short* __restrict__ IPB,
                         const unsigned short* __restrict__ IFB,
                         const unsigned short* __restrict__ WENC,
                         const float* __restrict__ taste_b, const float* __restrict__ intent_b,
                         float* __restrict__ outT, unsigned short* __restrict__ xbT,
                         float* __restrict__ outI, unsigned short* __restrict__ xbI,
                         unsigned short* __restrict__ IMB)
{
    __shared__ union {
        unsigned short AB[4][4096];
        unsigned short O[16384];
    } sm;
    const int tid = threadIdx.x;
    int f = xcd_swz(blockIdx.x, 1175);
    int seg, bx, by;
    if (f < 470)      { seg = 0; by = f >> 1; bx = f & 1; }
    else if (f < 940) { seg = 1; int g = f - 470; by = g >> 1; bx = g & 1; }
    else              { seg = 2; by = f - 940; bx = 0; }
    const unsigned short* A; const unsigned short* BT;
    const float* bias; float* D0; unsigned short* Db; int K, N;
    if (seg == 0)      { A = TFB; K = 768; BT = WENC + OFF_TASTE; bias = taste_b;  D0 = outT; Db = xbT; N = 256; }
    else if (seg == 1) { A = IPB; K = 32;  BT = WENC + OFF_INT;   bias = intent_b; D0 = outI; Db = xbI; N = 256; }
    else               { A = IFB; K = 512; BT = WENC + OFF_IMGU;  bias = nullptr;  D0 = nullptr; Db = IMB; N = 64; }
    const int row0 = by * 128, col0 = bx * 128;
    const int wid = tid >> 6, lane = tid & 63;
    const int wr = wid >> 1, wc = wid & 1;
    const int l16 = lane & 15, kg = lane >> 4;

    f32x4 acc[4][4];
    const f32x4 zero = {0.f, 0.f, 0.f, 0.f};
    #pragma unroll
    for (int i = 0; i < 4; ++i)
        #pragma unroll
        for (int j = 0; j < 4; ++j) acc[i][j] = zero;

    const int lrow = lane >> 2, lchk = lane & 3;
    const int gsw = (lchk ^ ((lrow >> 1) & 3)) * 8;
    int ar0 = min(row0 + wid * 32 + lrow, NNODE - 1);
    int ar1 = min(row0 + wid * 32 + 16 + lrow, NNODE - 1);
    const unsigned short* Ap0 = A + (size_t)ar0 * K + gsw;
    const unsigned short* Ap1 = A + (size_t)ar1 * K + gsw;
    int cB0 = min(col0 + wid * 32 + lrow, N - 1);
    int cB1 = min(col0 + wid * 32 + 16 + lrow, N - 1);
    const unsigned short* Bp0 = BT + (size_t)cB0 * K + gsw;
    const unsigned short* Bp1 = BT + (size_t)cB1 * K + gsw;
    const int ofs0 = wid * 1024, ofs1 = wid * 1024 + 512;
    const int rsw = ((l16 >> 1) & 3);
    const int nt = K >> 5;
    int cur = 0;

    #define STAGE_E(c, k0) do { \
        gl_lds16(Ap0 + (k0), &sm.AB[c][ofs0]); \
        gl_lds16(Ap1 + (k0), &sm.AB[c][ofs1]); \
        gl_lds16(Bp0 + (k0), &sm.AB[2 + (c)][ofs0]); \
        gl_lds16(Bp1 + (k0), &sm.AB[2 + (c)][ofs1]); \
    } while (0)

    STAGE_E(0, 0);
    for (int s = 0; s < nt; ++s) {
        if (s + 1 < nt) {
            STAGE_E(cur ^ 1, (s + 1) * 32);
            asm volatile("s_waitcnt vmcnt(4)" ::: "memory");
        } else {
            asm volatile("s_waitcnt vmcnt(0)" ::: "memory");
        }
        __builtin_amdgcn_s_barrier();
        asm volatile("" ::: "memory");
        short8 af[4], bfr[4];
        #pragma unroll
        for (int i = 0; i < 4; ++i) {
            af[i]  = *(const short8*)&sm.AB[cur][(wr * 64 + i * 16 + l16) * 32 + (kg ^ rsw) * 8];
            bfr[i] = *(const short8*)&sm.AB[2 + cur][(wc * 64 + i * 16 + l16) * 32 + (kg ^ rsw) * 8];
        }
        __builtin_amdgcn_s_setprio(1);
        #pragma unroll
        for (int i = 0; i < 4; ++i)
            #pragma unroll
            for (int j = 0; j < 4; ++j)
                acc[i][j] = __builtin_amdgcn_mfma_f32_16x16x32_bf16(af[i], bfr[j], acc[i][j], 0, 0, 0);
        __builtin_amdgcn_s_setprio(0);
        __builtin_amdgcn_s_barrier();
        asm volatile("" ::: "memory");
        cur ^= 1;
    }
    #undef STAGE_E

    #pragma unroll
    for (int j = 0; j < 4; ++j) {
        int lc = wc * 64 + j * 16 + l16;
        int cc = col0 + lc;
        float bv = (bias && cc < N) ? bias[cc] : 0.f;
        #pragma unroll
        for (int i = 0; i < 4; ++i) {
            #pragma unroll
            for (int r = 0; r < 4; ++r) {
                int lr = wr * 64 + i * 16 + kg * 4 + r;
                int rr = row0 + lr;
                float v = acc[i][j][r] + bv;
                if (D0 && cc < N && rr < NNODE) D0[(size_t)rr * N + cc] = v;
                sm.O[lr * 128 + ((((lc >> 3) ^ (lr & 7)) << 3) | (lc & 7))] = f2bf(v);
            }
        }
    }
    __syncthreads();
    {
        int nloc = N - col0; if (nloc > 128) nloc = 128;
        if (nloc >= 128) {
            int lr = tid >> 1, half = tid & 1;
            int rr = row0 + lr;
            if (rr < NNODE) {
                uint4* dst = (uint4*)&Db[(size_t)rr * N + col0 + half * 64];
                #pragma unroll
                for (int c = 0; c < 8; ++c) {
                    int ch = half * 8 + c;
                    dst[c] = *(const uint4*)&sm.O[lr * 128 + ((ch ^ (lr & 7)) << 3)];
                }
            }
        } else {
            if (tid < 128) {
                int lr = tid, rr = row0 + lr;
                if (rr < NNODE) {
                    uint4* dst = (uint4*)&Db[(size_t)rr * N + col0];
                    #pragma unroll
                    for (int c = 0; c < 8; ++c)
                        dst[c] = *(const uint4*)&sm.O[lr * 128 + ((c ^ (lr & 7)) << 3)];
                }
            }
        }
    }
}

// ---------------- merged KV+Q projection (BK=32), interleaved K|V output ----------------
__launch_bounds__(256)
__global__ void gemm_kvq768(const unsigned short* __restrict__ A,
                            const unsigned short* __restrict__ WALLl,
                            const float* __restrict__ bALLl,
                            unsigned short* __restrict__ KV,
                            unsigned short* __restrict__ QB)
{
    __shared__ union {
        unsigned short AB[4][4096];
        unsigned short O[16384];
    } sm;
    const int tid = threadIdx.x;
    int f = xcd_swz(blockIdx.x, 5664);
    int tt, bx, by;
    if (f < 2832) { tt = f / 1416; int r = f % 1416; by = r / 6; bx = r % 6; }
    else          { int g = f - 2832; tt = 2 + g / 944; int r = g % 944; by = r / 4; bx = r % 4; }
    const int row0 = by * 128, col0 = bx * 128;
    const int wid = tid >> 6, lane = tid & 63;
    const int wr = wid >> 1, wc = wid & 1;
    const int l16 = lane & 15, kg = lane >> 4;

    const unsigned short* Ab = A + (size_t)tt * SP;
    const unsigned short* BT = WALLl + (size_t)tt * 196608;
    const float* bias = bALLl + tt * 768;

    f32x4 acc[4][4];
    const f32x4 zero = {0.f, 0.f, 0.f, 0.f};
    #pragma unroll
    for (int i = 0; i < 4; ++i)
        #pragma unroll
        for (int j = 0; j < 4; ++j) acc[i][j] = zero;

    const int lrow = lane >> 2, lchk = lane & 3;
    const int gsw = (lchk ^ ((lrow >> 1) & 3)) * 8;
    const unsigned short* Ap0 = Ab + (size_t)(row0 + wid * 32 + lrow) * 256 + gsw;
    const unsigned short* Ap1 = Ab + (size_t)(row0 + wid * 32 + 16 + lrow) * 256 + gsw;
    const unsigned short* Bp0 = BT + (size_t)(col0 + wid * 32 + lrow) * 256 + gsw;
    const unsigned short* Bp1 = BT + (size_t)(col0 + wid * 32 + 16 + lrow) * 256 + gsw;
    const int ofs0 = wid * 1024, ofs1 = wid * 1024 + 512;
    const int rsw = ((l16 >> 1) & 3);
    int cur = 0;

    #define STAGE_K(c, k0) do { \
        gl_lds16(Ap0 + (k0), &sm.AB[c][ofs0]); \
        gl_lds16(Ap1 + (k0), &sm.AB[c][ofs1]); \
        gl_lds16(Bp0 + (k0), &sm.AB[2 + (c)][ofs0]); \
        gl_lds16(Bp1 + (k0), &sm.AB[2 + (c)][ofs1]); \
    } while (0)

    STAGE_K(0, 0);
    for (int s = 0; s < 8; ++s) {
        if (s + 1 < 8) {
            STAGE_K(cur ^ 1, (s + 1) * 32);
            asm volatile("s_waitcnt vmcnt(4)" ::: "memory");
        } else {
            asm volatile("s_waitcnt vmcnt(0)" ::: "memory");
        }
        __builtin_amdgcn_s_barrier();
        asm volatile("" ::: "memory");
        short8 af[4], bfr[4];
        #pragma unroll
        for (int i = 0; i < 4; ++i) {
            af[i]  = *(const short8*)&sm.AB[cur][(wr * 64 + i * 16 + l16) * 32 + (kg ^ rsw) * 8];
            bfr[i] = *(const short8*)&sm.AB[2 + cur][(wc * 64 + i * 16 + l16) * 32 + (kg ^ rsw) * 8];
        }
        __builtin_amdgcn_s_setprio(1);
        #pragma unroll
        for (int i = 0; i < 4; ++i)
            #pragma unroll
            for (int j = 0; j < 4; ++j)
                acc[i][j] = __builtin_amdgcn_mfma_f32_16x16x32_bf16(af[i], bfr[j], acc[i][j], 0, 0, 0);
        __builtin_amdgcn_s_setprio(0);
        __builtin_amdgcn_s_barrier();
        asm volatile("" ::: "memory");
        cur ^= 1;
    }
    #undef STAGE_K

    #pragma unroll
    for (int j = 0; j < 4; ++j) {
        int lc = wc * 64 + j * 16 + l16;
        float bv = bias[col0 + lc];
        #pragma unroll
        for (int i = 0; i < 4; ++i) {
            #pragma unroll
            for (int r = 0; r < 4; ++r) {
                int lr = wr * 64 + i * 16 + kg * 4 + r;
                float v = acc[i][j][r] + bv;
                sm.O[lr * 128 + ((((lc >> 3) ^ (lr & 7)) << 3) | (lc & 7))] = f2bf(v);
            }
        }
    }
    __syncthreads();
    {
        int dsel = bx >> 1;
        unsigned short* T; int ldT, cofs;
        if (dsel == 2) { T = QB + (size_t)tt * SP;  ldT = 256; cofs = (bx & 1) * 128; }
        else           { T = KV + (size_t)tt * SP2; ldT = 512; cofs = dsel * 256 + (bx & 1) * 128; }
        int lr = tid >> 1, half = tid & 1;
        int rr = row0 + lr;
        uint4* dst = (uint4*)&T[(size_t)rr * ldT + cofs + half * 64];
        #pragma unroll
        for (int c = 0; c < 8; ++c) {
            int ch = half * 8 + c;
            dst[c] = *(const uint4*)&sm.O[lr * 128 + ((ch ^ (lr & 7)) << 3)];
        }
    }
}

// 2-segment out-projection: seg0=USER, seg1=ITEM; bf16 resid in, bf16 pre-BN out
__launch_bounds__(256)
__global__ void gemm_outproj(const unsigned short* __restrict__ A,
                             const unsigned short* __restrict__ BT0,
                             const float* __restrict__ bias0,
                             const float* __restrict__ skipB,
                             const unsigned short* __restrict__ XBres,
                             unsigned short* __restrict__ Db, float* __restrict__ bns)
{
    __shared__ unsigned short AB[4][4096];
    const int tid = threadIdx.x;
    int bid = xcd_swz(blockIdx.y * 2 + blockIdx.x, 2 * gridDim.y);
    const int bx = bid % 2, by = bid / 2;
    const int tt = by / 236;
    const int row0 = by * 128, col0 = bx * 128;
    const int row0l = row0 - tt * MPD;
    const int wid = tid >> 6, lane = tid & 63;
    const int wr = wid >> 1, wc = wid & 1;
    const int l16 = lane & 15, kg = lane >> 4;

    const unsigned short* BT = BT0 + (size_t)tt * 65536;
    const float* bias = bias0 + tt * 256;
    const unsigned short* resid = XBres + (size_t)tt * SP;
    unsigned short* Dp = Db + (size_t)tt * SP;
    float* bnp = bns + tt * 512;

    f32x4 acc[4][4];
    const f32x4 zero = {0.f, 0.f, 0.f, 0.f};
    #pragma unroll
    for (int i = 0; i < 4; ++i)
        #pragma unroll
        for (int j = 0; j < 4; ++j) acc[i][j] = zero;

    const int lrow = lane >> 2, lchk = lane & 3;
    const int gsw = (lchk ^ ((lrow >> 1) & 3)) * 8;
    int ar0 = min(row0l + wid * 32 + lrow, NNODE - 1);
    int ar1 = min(row0l + wid * 32 + 16 + lrow, NNODE - 1);
    const unsigned short* Ap0 = A + (size_t)tt * S + (size_t)ar0 * 256 + gsw;
    const unsigned short* Ap1 = A + (size_t)tt * S + (size_t)ar1 * 256 + gsw;
    const unsigned short* Bp0 = BT + (size_t)(col0 + wid * 32 + lrow) * 256 + gsw;
    const unsigned short* Bp1 = BT + (size_t)(col0 + wid * 32 + 16 + lrow) * 256 + gsw;
    const int ofs0 = wid * 1024, ofs1 = wid * 1024 + 512;
    const int rsw = ((l16 >> 1) & 3);
    int cur = 0;

    #define STAGE_O(c, k0) do { \
        gl_lds16(Ap0 + (k0), &AB[c][ofs0]); \
        gl_lds16(Ap1 + (k0), &AB[c][ofs1]); \
        gl_lds16(Bp0 + (k0), &AB[2 + (c)][ofs0]); \
        gl_lds16(Bp1 + (k0), &AB[2 + (c)][ofs1]); \
    } while (0)

    STAGE_O(0, 0);
    for (int s = 0; s < 8; ++s) {
        if (s + 1 < 8) {
            STAGE_O(cur ^ 1, (s + 1) * 32);
            asm volatile("s_waitcnt vmcnt(4)" ::: "memory");
        } else {
            asm volatile("s_waitcnt vmcnt(0)" ::: "memory");
        }
        __builtin_amdgcn_s_barrier();
        asm volatile("" ::: "memory");
        short8 af[4], bfr[4];
        #pragma unroll
        for (int i = 0; i < 4; ++i) {
            af[i]  = *(const short8*)&AB[cur][(wr * 64 + i * 16 + l16) * 32 + (kg ^ rsw) * 8];
            bfr[i] = *(const short8*)&AB[2 + cur][(wc * 64 + i * 16 + l16) * 32 + (kg ^ rsw) * 8];
        }
        __builtin_amdgcn_s_setprio(1);
        #pragma unroll
        for (int i = 0; i < 4; ++i)
            #pragma unroll
            for (int j = 0; j < 4; ++j)
                acc[i][j] = __builtin_amdgcn_mfma_f32_16x16x32_bf16(af[i], bfr[j], acc[i][j], 0, 0, 0);
        __builtin_amdgcn_s_setprio(0);
        __builtin_amdgcn_s_barrier();
        asm volatile("" ::: "memory");
        cur ^= 1;
    }
    #undef STAGE_O

    float sg = 1.f / (1.f + __expf(-skipB[tt]));
    #pragma unroll
    for (int j = 0; j < 4; ++j) {
        int cc = col0 + wc * 64 + j * 16 + l16;
        float cs = 0.f, cs2 = 0.f;
        float bv = bias[cc];
        #pragma unroll
        for (int i = 0; i < 4; ++i) {
            #pragma unroll
            for (int r = 0; r < 4; ++r) {
                int lr = row0l + wr * 64 + i * 16 + kg * 4 + r;
                if (lr < NNODE) {
                    float v = acc[i][j][r] + bv;
                    float xo = b2f(resid[(size_t)lr * 256 + cc]);
                    float o = sg * v + (2.f - sg) * xo;
                    Dp[(size_t)lr * 256 + cc] = f2bf(o);
                    cs += o; cs2 += o * o;
                }
            }
        }
        cs  += __shfl_xor(cs, 16);  cs  += __shfl_xor(cs, 32);
        cs2 += __shfl_xor(cs2, 16); cs2 += __shfl_xor(cs2, 32);
        if (kg == 0) {
            atomicAdd(&bnp[cc], cs);
            atomicAdd(&bnp[256 + cc], cs2);
        }
    }
}

// ------------- CSR build -------------
__global__ void edge_hist2(const int* __restrict__ dstk, const int* __restrict__ srck,
                           int* __restrict__ cnt)
{
    int j = blockIdx.x * 256 + threadIdx.x;
    if (j < EBUY) atomicAdd(&cnt[dstk[j]], 1);
    else if (j < 2 * EBUY) atomicAdd(&cnt[NNODE + srck[j - EBUY]], 1);
}

#define SCAN_NB 30
#define SCAN_CH 1000
__global__ void scan_part(const int* __restrict__ cnt, int* __restrict__ bt)
{
    int set = blockIdx.y;
    const int* c = cnt + set * NNODE;
    int b = blockIdx.x;
    int i = b * SCAN_CH + threadIdx.x;
    int v = (threadIdx.x < SCAN_CH && i < NNODE) ? c[i] : 0;
    __shared__ int wsum[16];
    int lane = threadIdx.x & 63, wv = threadIdx.x >> 6;
    for (int o = 32; o; o >>= 1) v += __shfl_down(v, o);
    if (lane == 0) wsum[wv] = v;
    __syncthreads();
    if (threadIdx.x == 0) {
        int s = 0;
        for (int w = 0; w < 16; ++w) s += wsum[w];
        bt[set * 32 + b] = s;
    }
}

__global__ void scan_mid(int* __restrict__ bt, int* __restrict__ off_i, int* __restrict__ off_u)
{
    int set = threadIdx.x;
    if (set >= 2) return;
    int* b = bt + set * 32;
    int s = 0;
    for (int i = 0; i < SCAN_NB; ++i) { int c = b[i]; b[i] = s; s += c; }
    (set ? off_u : off_i)[NNODE] = s;
}

__global__ void scan_final(const int* __restrict__ cnt, const int* __restrict__ bt,
                           int* __restrict__ off_i, int* __restrict__ off_u,
                           int* __restrict__ cur_i, int* __restrict__ cur_u)
{
    int set = blockIdx.y;
    const int* c = cnt + set * NNODE;
    int* off = set ? off_u : off_i;
    int* cur = set ? cur_u : cur_i;
    int b = blockIdx.x;
    int i = b * SCAN_CH + threadIdx.x;
    int v = (threadIdx.x < SCAN_CH && i < NNODE) ? c[i] : 0;
    int lane = threadIdx.x & 63, wv = threadIdx.x >> 6;
    int x = v;
    for (int o = 1; o < 64; o <<= 1) { int t = __shfl_up(x, o); if (lane >= o) x += t; }
    __shared__ int wtot[16];
    if (lane == 63) wtot[wv] = x;
    __syncthreads();
    if (wv == 0) {
        int y = (lane < 16) ? wtot[lane] : 0;
        for (int o = 1; o < 16; o <<= 1) { int t = __shfl_up(y, o); if (lane >= o) y += t; }
        if (lane < 16) wtot[lane] = y;
    }
    __syncthreads();
    int wbase = (wv == 0) ? 0 : wtot[wv - 1];
    int excl = bt[set * 32 + b] + wbase + x - v;
    if (threadIdx.x < SCAN_CH && i < NNODE) { off[i] = excl; cur[i] = excl; }
}

__global__ void edge_place2(const int* __restrict__ dstk, const int* __restrict__ srck,
                            int* __restrict__ cur_i, int* __restrict__ cur_u,
                            int* __restrict__ src_i, int* __restrict__ src_u)
{
    int j = blockIdx.x * 256 + threadIdx.x;
    if (j < EBUY) {
        int pos = atomicAdd(&cur_i[dstk[j]], 1);
        src_i[pos] = srck[j];
    } else if (j < 2 * EBUY) {
        int j2 = j - EBUY;
        int pos = atomicAdd(&cur_u[srck[j2]], 1);
        src_u[pos] = dstk[j2];
    }
}

// both attention sides; user -> AGB seg0, item -> AGB seg1; interleaved KV rows; depth-2 prefetch
__launch_bounds__(256)
__global__ void attn_both(const unsigned short* __restrict__ QB,
                          const unsigned short* __restrict__ KV,
                          const int* __restrict__ off_i, const int* __restrict__ src_i,
                          const int* __restrict__ off_u, const int* __restrict__ src_u,
                          const float* __restrict__ pR,
                          unsigned short* __restrict__ AGB)
{
    int gw = (blockIdx.x * 256 + threadIdx.x) >> 6;
    int lane = threadIdx.x & 63;
    if (gw >= 2 * NNODE) return;
    int h = lane >> 4;
    const bool item = gw < NNODE;
    const int wid = item ? gw : gw - NNODE;
    const unsigned short* Qd  = item ? QB + SP : QB;
    const unsigned short* KVs = item ? KV : KV + SP2;
    const int* roff = item ? off_i : off_u;
    const int* srcA = item ? src_i : src_u;
    unsigned short* outp = AGB + (item ? S : 0);

    ushort4 qb = *(const ushort4*)(Qd + (size_t)wid * 256 + lane * 4);
    float4 q = {b2f(qb.x), b2f(qb.y), b2f(qb.z), b2f(qb.w)};
    float m = -INFINITY, s = 0.f;
    float4 acc = {0.f, 0.f, 0.f, 0.f};

    #define AT_STEP(KBV, VBV, PSCALE) do { \
        float d = q.x * b2f((KBV).x) + q.y * b2f((KBV).y) + q.z * b2f((KBV).z) + q.w * b2f((KBV).w); \
        for (int off = 8; off; off >>= 1) d += __shfl_xor(d, off, 16); \
        float lg = d * (PSCALE); \
        float mn = fmaxf(m, lg); \
        float so = __expf(m - mn); \
        float ev = __expf(lg - mn); \
        s = s * so + ev; \
        acc.x = acc.x * so + ev * b2f((VBV).x); \
        acc.y = acc.y * so + ev * b2f((VBV).y); \
        acc.z = acc.z * so + ev * b2f((VBV).z); \
        acc.w = acc.w * so + ev * b2f((VBV).w); \
        m = mn; \
    } while (0)

    if (item) {
        #pragma unroll
        for (int e = 0; e < 3; ++e) {
            const unsigned short* kvrow = KV + (size_t)(2 + e) * SP2 + (size_t)wid * 512;
            ushort4 kb = *(const ushort4*)(kvrow + lane * 4);
            ushort4 vv = *(const ushort4*)(kvrow + 256 + lane * 4);
            AT_STEP(kb, vv, pR[e * 4 + h] * 0.125f);
        }
    }

    float pb = pR[(item ? 12 : 16) + h] * 0.125f;
    int j0 = roff[wid], j1 = roff[wid + 1];
    ushort4 kA = {0,0,0,0}, vA = {0,0,0,0}, kB = {0,0,0,0}, vB = {0,0,0,0};
    if (j0 < j1) {
        const unsigned short* r0 = KVs + (size_t)srcA[j0] * 512;
        kA = *(const ushort4*)(r0 + lane * 4);
        vA = *(const ushort4*)(r0 + 256 + lane * 4);
    }
    if (j0 + 1 < j1) {
        const unsigned short* r1 = KVs + (size_t)srcA[j0 + 1] * 512;
        kB = *(const ushort4*)(r1 + lane * 4);
        vB = *(const ushort4*)(r1 + 256 + lane * 4);
    }
    int j = j0;
    while (j < j1) {
        ushort4 ck = kA, cv = vA;
        if (j + 2 < j1) {
            const unsigned short* rn = KVs + (size_t)srcA[j + 2] * 512;
            kA = *(const ushort4*)(rn + lane * 4);
            vA = *(const ushort4*)(rn + 256 + lane * 4);
        }
        AT_STEP(ck, cv, pb);
        ++j;
        if (j >= j1) break;
        ck = kB; cv = vB;
        if (j + 2 < j1) {
            const unsigned short* rn = KVs + (size_t)srcA[j + 2] * 512;
            kB = *(const ushort4*)(rn + lane * 4);
            vB = *(const ushort4*)(rn + 256 + lane * 4);
        }
        AT_STEP(ck, cv, pb);
        ++j;
    }
    #undef AT_STEP

    float inv = 1.f / (s + 1e-16f);
    ushort4 o4;
    o4.x = f2bf(gelu_f(acc.x * inv));
    o4.y = f2bf(gelu_f(acc.y * inv));
    o4.z = f2bf(gelu_f(acc.z * inv));
    o4.w = f2bf(gelu_f(acc.w * inv));
    *(ushort4*)(outp + (size_t)wid * 256 + lane * 4) = o4;
}

// ------------- batch-norm -------------
#define BNB 512
__global__ void bn_stats2(const float* __restrict__ SCRf, float* __restrict__ part)
{
    int tt = blockIdx.y;
    const float* x = SCRf + (size_t)tt * SP;
    int col = threadIdx.x;
    int b = blockIdx.x;
    float s = 0.f, s2 = 0.f;
    int r = b;
    for (; r + 3 * BNB < NNODE; r += 4 * BNB) {
        float v0 = x[(size_t)r * 256 + col];
        float v1 = x[(size_t)(r + BNB) * 256 + col];
        float v2 = x[(size_t)(r + 2 * BNB) * 256 + col];
        float v3 = x[(size_t)(r + 3 * BNB) * 256 + col];
        s += v0 + v1 + v2 + v3;
        s2 += v0 * v0 + v1 * v1 + v2 * v2 + v3 * v3;
    }
    for (; r < NNODE; r += BNB) {
        float v = x[(size_t)r * 256 + col];
        s += v; s2 += v * v;
    }
    part[((size_t)tt * BNB + b) * 512 + col] = s;
    part[((size_t)tt * BNB + b) * 512 + 256 + col] = s2;
}

__global__ void bn_fin2(const float* __restrict__ part,
                        const float* __restrict__ g0, const float* __restrict__ b0,
                        const float* __restrict__ g1, const float* __restrict__ b1,
                        float* __restrict__ scsh)
{
    int tid = threadIdx.x;
    int tt = tid >> 8, col = tid & 255;
    const float* p = part + (size_t)tt * BNB * 512;
    float s = 0.f, s2 = 0.f;
    #pragma unroll 4
    for (int b = 0; b < BNB; ++b) { s += p[b * 512 + col]; s2 += p[b * 512 + 256 + col]; }
    float mu = s / (float)NNODE;
    float var = s2 / (float)NNODE - mu * mu;
    float sc = rsqrtf(var + 1e-5f) * (tt ? g1 : g0)[col];
    scsh[tt * 512 + col] = sc;
    scsh[tt * 512 + 256 + col] = (tt ? b1 : b0)[col] - mu * sc;
}

__global__ void bn_find2(const float* __restrict__ bns,
                         const float* __restrict__ g01, const float* __restrict__ b01,
                         float* __restrict__ scsh)
{
    int tid = threadIdx.x;
    int tt = tid >> 8, col = tid & 255;
    float s = bns[tt * 512 + col], s2 = bns[tt * 512 + 256 + col];
    float mu = s / (float)NNODE;
    float var = s2 / (float)NNODE - mu * mu;
    float sc = rsqrtf(var + 1e-5f) * g01[tt * 256 + col];
    scsh[tt * 512 + col] = sc;
    scsh[tt * 512 + 256 + col] = b01[tt * 256 + col] - mu * sc;
}

// f32-input apply (encoder path); zeroes bnsZ for the next out-proj if non-null
template<int WF32>
__global__ void bn_apply2(const float* __restrict__ SCRf, const float* __restrict__ scsh,
                          float* __restrict__ out, unsigned short* __restrict__ XBall,
                          float* __restrict__ bnsZ)
{
    if (bnsZ && blockIdx.x == 0) {
        float4 z = {0.f, 0.f, 0.f, 0.f};
        ((float4*)bnsZ)[threadIdx.x] = z;   // 256 threads x 16B = 1024 floats
    }
    const int Q4 = NNODE * 64;
    for (int i = blockIdx.x * 256 + threadIdx.x; i < 2 * Q4; i += gridDim.x * 256) {
        int tt = (i >= Q4) ? 1 : 0;
        int local = i - tt * Q4;
        int c4 = local & 63;
        float4 sc4 = *(const float4*)&scsh[tt * 512 + c4 * 4];
        float4 sh4 = *(const float4*)&scsh[tt * 512 + 256 + c4 * 4];
        float4 v = ((const float4*)(SCRf + (size_t)tt * SP))[local];
        v.x = fmaxf(v.x * sc4.x + sh4.x, 0.f);
        v.y = fmaxf(v.y * sc4.y + sh4.y, 0.f);
        v.z = fmaxf(v.z * sc4.z + sh4.z, 0.f);
        v.w = fmaxf(v.w * sc4.w + sh4.w, 0.f);
        if (WF32) ((float4*)(out + (size_t)tt * S))[local] = v;
        ushort4 u = {f2bf(v.x), f2bf(v.y), f2bf(v.z), f2bf(v.w)};
        ((ushort4*)(XBall + (size_t)tt * SP))[local] = u;
    }
}

// bf16-input apply (layer path); zeroes bnsZ for the next out-proj if non-null
template<int WF32>
__global__ void bn_apply2b(const unsigned short* __restrict__ SCRb, const float* __restrict__ scsh,
                           float* __restrict__ out, unsigned short* __restrict__ XBall,
                           float* __restrict__ bnsZ)
{
    if (bnsZ && blockIdx.x == 0) {
        float4 z = {0.f, 0.f, 0.f, 0.f};
        ((float4*)bnsZ)[threadIdx.x] = z;
    }
    const int Q4 = NNODE * 64;
    for (int i = blockIdx.x * 256 + threadIdx.x; i < 2 * Q4; i += gridDim.x * 256) {
        int tt = (i >= Q4) ? 1 : 0;
        int local = i - tt * Q4;
        int c4 = local & 63;
        float4 sc4 = *(const float4*)&scsh[tt * 512 + c4 * 4];
        float4 sh4 = *(const float4*)&scsh[tt * 512 + 256 + c4 * 4];
        ushort4 b4 = ((const ushort4*)(SCRb + (size_t)tt * SP))[local];
        float4 v = {b2f(b4.x), b2f(b4.y), b2f(b4.z), b2f(b4.w)};
        v.x = fmaxf(v.x * sc4.x + sh4.x, 0.f);
        v.y = fmaxf(v.y * sc4.y + sh4.y, 0.f);
        v.z = fmaxf(v.z * sc4.z + sh4.z, 0.f);
        v.w = fmaxf(v.w * sc4.w + sh4.w, 0.f);
        if (WF32) ((float4*)(out + (size_t)tt * S))[local] = v;
        ushort4 u = {f2bf(v.x), f2bf(v.y), f2bf(v.z), f2bf(v.w)};
        ((ushort4*)(XBall + (size_t)tt * SP))[local] = u;
    }
}

extern "C" void kernel_launch(void* const* d_in, const int* in_sizes, int n_in,
                              void* d_out, int out_size, void* d_ws, size_t ws_size,
                              hipStream_t stream)
{
    const int*   user_id    = (const int*)d_in[0];
    const int*   item_id    = (const int*)d_in[1];
    const int*   buys_src   = (const int*)d_in[2];
    const int*   buys_dst   = (const int*)d_in[3];
    const float* image_feat = (const float*)d_in[4];
    const float* taste_feat = (const float*)d_in[5];
    const float* intent_feat= (const float*)d_in[6];
    const float* user_emb   = (const float*)d_in[7];
    const float* user_W     = (const float*)d_in[8];
    const float* user_b     = (const float*)d_in[9];
    const float* user_bn_g  = (const float*)d_in[10];
    const float* user_bn_b  = (const float*)d_in[11];
    const float* item_emb   = (const float*)d_in[12];
    const float* item_W     = (const float*)d_in[13];
    const float* item_b     = (const float*)d_in[14];
    const float* item_bn_g  = (const float*)d_in[15];
    const float* item_bn_b  = (const float*)d_in[16];
    const float* img_U      = (const float*)d_in[17];
    const float* img_V      = (const float*)d_in[18];
    const float* img_b      = (const float*)d_in[19];
    const float* taste_W    = (const float*)d_in[20];
    const float* taste_b    = (const float*)d_in[21];
    const float* intent_W   = (const float*)d_in[22];
    const float* intent_b   = (const float*)d_in[23];
    const float* kqv_W      = (const float*)d_in[24];
    const float* kqv_b      = (const float*)d_in[25];
    const float* out_W      = (const float*)d_in[26];
    const float* out_b      = (const float*)d_in[27];
    const float* k_rel      = (const float*)d_in[28];
    const float* v_rel      = (const float*)d_in[29];
    const float* p_rel      = (const float*)d_in[30];
    const float* skip       = (const float*)d_in[31];
    const float* fbn_g      = (const float*)d_in[32];
    const float* fbn_b      = (const float*)d_in[33];

    float* out = (float*)d_out;
    float* ws  = (float*)d_ws;

    float* SCRf = ws;
    float* BNSp = SCRf + 2 * SP;
    float* BNS  = BNSp + 2 * BNB * 512;
    float* SCSH = BNS + 1024;
    float* bALL = SCSH + 1024;
    unsigned short* QB    = (unsigned short*)(bALL + 7680);
    unsigned short* XBall = QB + 2 * SP;
    unsigned short* KVall = XBall + 5 * SP;
    unsigned short* AGB   = KVall + 5 * SP2;
    unsigned short* IMB   = AGB + 2 * S;
    unsigned short* IPB   = IMB + (size_t)NNODE * 64;
    unsigned short* WALL  = IPB + (size_t)NNODE * 32;
    unsigned short* WENC  = WALL + (size_t)10 * 196608;
    int* cnt   = (int*)(WENC + WENC_TOT);
    int* off_i = cnt + 2 * NNODE;
    int* off_u = off_i + NNODE + 1;
    int* cur_i = off_u + NNODE + 1;
    int* cur_u = cur_i + NNODE;
    int* src_i = cur_u + NNODE;
    int* src_u = src_i + EBUY;
    int* bt    = src_u + EBUY;

    size_t need = (size_t)((char*)(bt + 64) - (char*)ws);
    if (ws_size < need) return;

    unsigned short* TFB  = (unsigned short*)SCRf;   // encoder-phase aliases
    unsigned short* IFB  = QB;
    unsigned short* SCRb = (unsigned short*)SCRf;   // layer-phase bf16 pre-BN scratch

    hipMemsetAsync(cnt, 0, 2 * NNODE * 4, stream);
    edge_hist2<<<(2 * EBUY + 255) / 256, 256, 0, stream>>>(buys_dst, buys_src, cnt);
    scan_part<<<dim3(SCAN_NB, 2), 1024, 0, stream>>>(cnt, bt);
    scan_mid<<<1, 64, 0, stream>>>(bt, off_i, off_u);
    scan_final<<<dim3(SCAN_NB, 2), 1024, 0, stream>>>(cnt, bt, off_i, off_u, cur_i, cur_u);
    edge_place2<<<(2 * EBUY + 255) / 256, 256, 0, stream>>>(buys_dst, buys_src, cur_i, cur_u, src_i, src_u);

    wtconv_all<<<(WENC_TOT + 255) / 256, 256, 0, stream>>>(taste_W, intent_W, img_U, img_V,
                                                           user_W, item_W, out_W, WENC);
    build_kqv<<<dim3(771, 10), 256, 0, stream>>>(kqv_W, kqv_b, k_rel, v_rel, WALL, bALL);
    conv_pad<<<(NNODE * 32 + 255) / 256, 256, 0, stream>>>(intent_feat, IPB, NNODE, 20, 32);
    conv2bf<<<2048, 256, 0, stream>>>(taste_feat, 5760000, TFB, image_feat, 3840000, IFB);

    // merged taste | intent | imgU
    hipLaunchKernelGGL(gemm_enc, dim3(1175), dim3(256), 0, stream,
        TFB, IPB, IFB, WENC, taste_b, intent_b,
        out + 2*S, XBall + 2*SP, out + 3*S, XBall + 3*SP, IMB);
    // imgV (depends on IMB)
    hipLaunchKernelGGL((gemm_mfma<0,0,0>), dim3(2,235), dim3(256), 0, stream,
        IMB, nullptr, nullptr, nullptr, WENC + OFF_IMGV, img_b, nullptr,
        out + 4*S, XBall + 4*SP, NNODE, 256, 64);
    // user/item (f32 gather; writes SCRf after TFB consumed)
    hipLaunchKernelGGL((gemm_mfma<1,1,6>), dim3(2,472), dim3(256), 0, stream,
        user_emb, item_emb, user_id, item_id, WENC + OFF_USER, user_b, item_b,
        SCRf, nullptr, 2*MPD, 256, 64);
    bn_stats2<<<dim3(BNB, 2), 256, 0, stream>>>(SCRf, BNSp);
    bn_fin2<<<1, 512, 0, stream>>>(BNSp, user_bn_g, user_bn_b, item_bn_g, item_bn_b, SCSH);
    bn_apply2<0><<<960, 256, 0, stream>>>(SCRf, SCSH, out, XBall, BNS);   // zeroes BNS for layer 0

    for (int l = 0; l < 2; ++l) {
        hipLaunchKernelGGL(gemm_kvq768, dim3(5664), dim3(256), 0, stream,
            XBall, WALL + (size_t)l*5*196608, bALL + l*5*768, KVall, QB);
        hipLaunchKernelGGL(attn_both, dim3((2*NNODE*64 + 255)/256), dim3(256), 0, stream,
            QB, KVall, off_i, src_i, off_u, src_u, p_rel + l*20, AGB);
        hipLaunchKernelGGL(gemm_outproj, dim3(2, 472), dim3(256), 0, stream,
            AGB, WENC + OFF_OUTW + (size_t)l*2*65536, out_b + (size_t)l*5*256,
            skip + l*5, XBall, SCRb, BNS);
        bn_find2<<<1, 512, 0, stream>>>(BNS, fbn_g + (size_t)l*2*256, fbn_b + (size_t)l*2*256, SCSH);
        if (l == 0) bn_apply2b<0><<<960, 256, 0, stream>>>(SCRb, SCSH, out, XBall, BNS);  // zero for layer 1
        else        bn_apply2b<1><<<960, 256, 0, stream>>>(SCRb, SCSH, out, XBall, nullptr);
    }
}

// Round 18
// 881.687 us; speedup vs baseline: 1.0109x; 1.0109x over previous
//
#include <hip/hip_runtime.h>
#include <math.h>

#define HID 256
#define EBUY 200000
#define NNODE 30000
#define MPD 30208
static const size_t S   = (size_t)NNODE * HID;
static const size_t SP  = (size_t)MPD * HID;
static const size_t SP2 = (size_t)MPD * 512;

typedef __attribute__((ext_vector_type(8))) short  short8;
typedef __attribute__((ext_vector_type(4))) float  f32x4;

#define OFF_TASTE 0
#define OFF_INT   196608
#define OFF_IMGU  204800
#define OFF_IMGV  237568
#define OFF_USER  253952
#define OFF_ITEM  270336
#define OFF_OUTW  286720
#define WENC_TOT  548864

__device__ __forceinline__ float gelu_f(float x) {
    return 0.5f * x * (1.0f + erff(x * 0.70710678118654752f));
}
__device__ __forceinline__ unsigned short f2bf(float f) {
    unsigned u = __float_as_uint(f);
    u = (u + 0x7FFFu + ((u >> 16) & 1u)) >> 16;
    return (unsigned short)u;
}
__device__ __forceinline__ float b2f(unsigned short us) {
    return __uint_as_float((unsigned)us << 16);
}
__device__ __forceinline__ void gl_lds16(const unsigned short* g, unsigned short* l) {
    __builtin_amdgcn_global_load_lds(
        (const __attribute__((address_space(1))) unsigned int*)g,
        (__attribute__((address_space(3))) unsigned int*)l, 16, 0, 0);
}
__device__ __forceinline__ int xcd_swz(int bid, int nwg) {
    int q = nwg >> 3, r = nwg & 7;
    int xc = bid & 7, i = bid >> 3;
    int base = (xc < r) ? xc * (q + 1) : r * (q + 1) + (xc - r) * q;
    return base + i;
}

// ---------------- conversions / weight prep ----------------
__global__ void conv_pad(const float* __restrict__ in, unsigned short* __restrict__ o,
                         int M, int K, int Kpad)
{
    int i = blockIdx.x * 256 + threadIdx.x;
    if (i >= M * Kpad) return;
    int r = i / Kpad, k = i % Kpad;
    o[i] = (k < K) ? f2bf(in[(size_t)r * K + k]) : (unsigned short)0;
}

__global__ void conv2bf(const float* __restrict__ a, int na4, unsigned short* __restrict__ oa,
                        const float* __restrict__ b, int nb4, unsigned short* __restrict__ ob)
{
    int total = na4 + nb4;
    for (int i = blockIdx.x * 256 + threadIdx.x; i < total; i += gridDim.x * 256) {
        if (i < na4) {
            float4 v = ((const float4*)a)[i];
            ushort4 u = {f2bf(v.x), f2bf(v.y), f2bf(v.z), f2bf(v.w)};
            ((ushort4*)oa)[i] = u;
        } else {
            int j = i - na4;
            float4 v = ((const float4*)b)[j];
            ushort4 u = {f2bf(v.x), f2bf(v.y), f2bf(v.z), f2bf(v.w)};
            ((ushort4*)ob)[j] = u;
        }
    }
}

__global__ void wtconv_all(const float* __restrict__ taste_W, const float* __restrict__ intent_W,
                           const float* __restrict__ img_U, const float* __restrict__ img_V,
                           const float* __restrict__ user_W, const float* __restrict__ item_W,
                           const float* __restrict__ out_W, unsigned short* __restrict__ WENC)
{
    int i = blockIdx.x * 256 + threadIdx.x;
    if (i >= WENC_TOT) return;
    const float* W; int K, N, Kpad, idx;
    if (i < OFF_INT)        { W = taste_W;  K = 768; N = 256; Kpad = 768; idx = i - OFF_TASTE; }
    else if (i < OFF_IMGU)  { W = intent_W; K = 20;  N = 256; Kpad = 32;  idx = i - OFF_INT; }
    else if (i < OFF_IMGV)  { W = img_U;    K = 512; N = 64;  Kpad = 512; idx = i - OFF_IMGU; }
    else if (i < OFF_USER)  { W = img_V;    K = 64;  N = 256; Kpad = 64;  idx = i - OFF_IMGV; }
    else if (i < OFF_ITEM)  { W = user_W;   K = 64;  N = 256; Kpad = 64;  idx = i - OFF_USER; }
    else if (i < OFF_OUTW)  { W = item_W;   K = 64;  N = 256; Kpad = 64;  idx = i - OFF_ITEM; }
    else {
        int k = (i - OFF_OUTW) >> 16;
        int l = k >> 1, d = k & 1;
        W = out_W + (size_t)(l * 5 + d) * 65536;
        K = 256; N = 256; Kpad = 256; idx = (i - OFF_OUTW) & 65535;
    }
    int n = idx / Kpad, kk = idx % Kpad;
    WENC[i] = (kk < K) ? f2bf(W[(size_t)kk * N + n]) : (unsigned short)0;
}

__global__ void build_kqv(const float* __restrict__ kqv_W, const float* __restrict__ kqv_b,
                          const float* __restrict__ k_rel, const float* __restrict__ v_rel,
                          unsigned short* __restrict__ WALL, float* __restrict__ bALL)
{
    int s = blockIdx.y;
    int l = s / 5, t = s % 5;
    static const int es[5] = {3, 4, 0, 1, 2};
    int e = es[t];
    int tid = blockIdx.x * 256 + threadIdx.x;
    if (tid >= 257 * 768) return;
    int r = tid / 768, c = tid % 768;
    int cb = c >> 8, cc = c & 255;
    int h = cc >> 6, dd = cc & 63;
    const float* W = kqv_W + (size_t)s * 196608;
    const float* bv = kqv_b + (size_t)s * 768;
    const float* Wrow = (r < 256) ? (W + (size_t)r * 768) : bv;
    if (cb == 1) {
        if (t >= 2) return;
        float outv = Wrow[256 + cc];
        if (r < 256) WALL[(size_t)s * 196608 + (size_t)(512 + cc) * 256 + r] = f2bf(outv);
        else         bALL[s * 768 + 512 + cc] = outv;
        return;
    }
    const float* R = ((cb == 0) ? k_rel : v_rel) + (size_t)(l * 5 + e) * 16384 + (size_t)h * 4096;
    int sb = (cb == 0) ? 0 : 512;
    float sum = 0.f;
    #pragma unroll 8
    for (int d = 0; d < 64; ++d)
        sum += Wrow[sb + h * 64 + d] * R[d * 64 + dd];
    int col = (cb == 0) ? cc : 256 + cc;
    if (r < 256) WALL[(size_t)s * 196608 + (size_t)col * 256 + r] = f2bf(sum);
    else         bALL[s * 768 + col] = sum;
}

// ---------------- unified 128x128 bf16 MFMA GEMM (BK=32, depth-1) ----------------
template<int AF32, int GATH2, int EPI>
__launch_bounds__(256)
__global__ void gemm_mfma(const void* __restrict__ Ap, const void* __restrict__ Ap2,
                          const int* __restrict__ g1, const int* __restrict__ g2,
                          const unsigned short* __restrict__ BT0,
                          const float* __restrict__ bias0, const float* __restrict__ bias1,
                          float* __restrict__ D0, unsigned short* __restrict__ Db,
                          int M, int N, int K)
{
    __shared__ union {
        unsigned short AB[4][4096];
        unsigned short O[16384];
    } sm;
    const int tid = threadIdx.x;
    const int gx = gridDim.x;
    int bid = xcd_swz(blockIdx.y * gx + blockIdx.x, gx * gridDim.y);
    const int bx = bid % gx, by = bid / gx;
    const int row0 = by * 128, col0 = bx * 128;
    const int wid = tid >> 6, lane = tid & 63;
    const int wr = wid >> 1, wc = wid & 1;
    const int l16 = lane & 15, kg = lane >> 4;
    const int tt = GATH2 ? (by / 236) : 0;

    const unsigned short* BT = BT0;
    if (GATH2 && tt) BT = BT0 + 16384;
    const float* bias = bias0;
    if (GATH2) bias = tt ? bias1 : bias0;

    f32x4 acc[4][4];
    const f32x4 zero = {0.f, 0.f, 0.f, 0.f};
    #pragma unroll
    for (int i = 0; i < 4; ++i)
        #pragma unroll
        for (int j = 0; j < 4; ++j) acc[i][j] = zero;

    const int lrow = lane >> 2, lchk = lane & 3;
    const int gsw = (lchk ^ ((lrow >> 1) & 3)) * 8;
    int cB0 = min(col0 + wid * 32 + lrow, N - 1);
    int cB1 = min(col0 + wid * 32 + 16 + lrow, N - 1);
    const unsigned short* Bp0 = BT + (size_t)cB0 * K + gsw;
    const unsigned short* Bp1 = BT + (size_t)cB1 * K + gsw;
    const int ofs0 = wid * 1024, ofs1 = wid * 1024 + 512;

    const unsigned short* Ap0b = nullptr; const unsigned short* Ap1b = nullptr;
    const float* Af0 = nullptr; const float* Af1 = nullptr;
    const int rA0 = tid >> 2, rA1 = (tid >> 2) + 64;
    const int q0 = tid & 3;
    const int wsw = (q0 ^ ((rA0 >> 1) & 3)) * 8;
    if (GATH2) {
        int lr0 = row0 + rA0 - tt * MPD; if (lr0 >= NNODE) lr0 = NNODE - 1;
        int lr1 = row0 + rA1 - tt * MPD; if (lr1 >= NNODE) lr1 = NNODE - 1;
        const int* gA = tt ? g2 : g1;
        const float* Abase = tt ? (const float*)Ap2 : (const float*)Ap;
        Af0 = Abase + (size_t)gA[lr0] * K;
        Af1 = Abase + (size_t)gA[lr1] * K;
    } else if (AF32) {
        Af0 = (const float*)Ap + (size_t)min(row0 + rA0, M - 1) * K;
        Af1 = (const float*)Ap + (size_t)min(row0 + rA1, M - 1) * K;
    } else {
        int rr0 = min(row0 + wid * 32 + lrow, M - 1);
        int rr1 = min(row0 + wid * 32 + 16 + lrow, M - 1);
        Ap0b = (const unsigned short*)Ap + (size_t)rr0 * K + gsw;
        Ap1b = (const unsigned short*)Ap + (size_t)rr1 * K + gsw;
    }

    const int nt = K >> 5;
    const int rsw = ((l16 >> 1) & 3);

    #define STAGE_F32(c, k0) do { \
        float4 x0 = *(const float4*)&Af0[(k0) + q0 * 8]; \
        float4 x1 = *(const float4*)&Af0[(k0) + q0 * 8 + 4]; \
        float4 y0 = *(const float4*)&Af1[(k0) + q0 * 8]; \
        float4 y1 = *(const float4*)&Af1[(k0) + q0 * 8 + 4]; \
        ushort4 u0 = {f2bf(x0.x), f2bf(x0.y), f2bf(x0.z), f2bf(x0.w)}; \
        ushort4 u1 = {f2bf(x1.x), f2bf(x1.y), f2bf(x1.z), f2bf(x1.w)}; \
        ushort4 w0 = {f2bf(y0.x), f2bf(y0.y), f2bf(y0.z), f2bf(y0.w)}; \
        ushort4 w1 = {f2bf(y1.x), f2bf(y1.y), f2bf(y1.z), f2bf(y1.w)}; \
        *(ushort4*)&sm.AB[c][rA0 * 32 + wsw]     = u0; \
        *(ushort4*)&sm.AB[c][rA0 * 32 + wsw + 4] = u1; \
        *(ushort4*)&sm.AB[c][rA1 * 32 + wsw]     = w0; \
        *(ushort4*)&sm.AB[c][rA1 * 32 + wsw + 4] = w1; \
        gl_lds16(Bp0 + (k0), &sm.AB[2 + (c)][ofs0]); \
        gl_lds16(Bp1 + (k0), &sm.AB[2 + (c)][ofs1]); \
    } while (0)

    #define STAGE_A(c, k0) do { \
        gl_lds16(Ap0b + (k0), &sm.AB[c][ofs0]); \
        gl_lds16(Ap1b + (k0), &sm.AB[c][ofs1]); \
        gl_lds16(Bp0 + (k0), &sm.AB[2 + (c)][ofs0]); \
        gl_lds16(Bp1 + (k0), &sm.AB[2 + (c)][ofs1]); \
    } while (0)

    #define LOADFRAG(c) do { \
        _Pragma("unroll") \
        for (int i = 0; i < 4; ++i) { \
            af[i]  = *(const short8*)&sm.AB[c][(wr * 64 + i * 16 + l16) * 32 + (kg ^ rsw) * 8]; \
            bfr[i] = *(const short8*)&sm.AB[2 + (c)][(wc * 64 + i * 16 + l16) * 32 + (kg ^ rsw) * 8]; \
        } \
    } while (0)

    #define MMAS() do { \
        _Pragma("unroll") \
        for (int i = 0; i < 4; ++i) \
            _Pragma("unroll") \
            for (int j = 0; j < 4; ++j) \
                acc[i][j] = __builtin_amdgcn_mfma_f32_16x16x32_bf16(af[i], bfr[j], acc[i][j], 0, 0, 0); \
    } while (0)

    if (AF32 || GATH2) {
        STAGE_F32(0, 0);
        __syncthreads();
        int cur = 0;
        for (int s = 0; s < nt; ++s) {
            if (s + 1 < nt) STAGE_F32(cur ^ 1, (s + 1) * 32);
            short8 af[4], bfr[4];
            LOADFRAG(cur);
            MMAS();
            __syncthreads();
            cur ^= 1;
        }
    } else {
        STAGE_A(0, 0);
        int cur = 0;
        for (int s = 0; s < nt; ++s) {
            if (s + 1 < nt) {
                STAGE_A(cur ^ 1, (s + 1) * 32);
                asm volatile("s_waitcnt vmcnt(4)" ::: "memory");
            } else {
                asm volatile("s_waitcnt vmcnt(0)" ::: "memory");
            }
            __builtin_amdgcn_s_barrier();
            asm volatile("" ::: "memory");
            short8 af[4], bfr[4];
            LOADFRAG(cur);
            __builtin_amdgcn_s_setprio(1);
            MMAS();
            __builtin_amdgcn_s_setprio(0);
            __builtin_amdgcn_s_barrier();
            asm volatile("" ::: "memory");
            cur ^= 1;
        }
    }
    #undef STAGE_F32
    #undef STAGE_A
    #undef LOADFRAG
    #undef MMAS

    #pragma unroll
    for (int j = 0; j < 4; ++j) {
        int lc = wc * 64 + j * 16 + l16;
        int cc = col0 + lc;
        float bv = (bias && cc < N) ? bias[cc] : 0.f;
        #pragma unroll
        for (int i = 0; i < 4; ++i) {
            #pragma unroll
            for (int r = 0; r < 4; ++r) {
                int lr = wr * 64 + i * 16 + kg * 4 + r;
                int rr = row0 + lr;
                float v = acc[i][j][r] + bv;
                if (EPI == 0) {
                    if (D0 && cc < N && rr < M) D0[(size_t)rr * N + cc] = v;
                    sm.O[lr * 128 + ((((lc >> 3) ^ (lr & 7)) << 3) | (lc & 7))] = f2bf(v);
                } else if (EPI == 6) {
                    D0[(size_t)rr * 256 + cc] = v;
                }
            }
        }
    }
    if (EPI == 0) {
        __syncthreads();
        int nloc = N - col0; if (nloc > 128) nloc = 128;
        if (nloc >= 128) {
            int lr = tid >> 1, half = tid & 1;
            int rr = row0 + lr;
            if (rr < M) {
                uint4* dst = (uint4*)&Db[(size_t)rr * N + col0 + half * 64];
                #pragma unroll
                for (int c = 0; c < 8; ++c) {
                    int ch = half * 8 + c;
                    dst[c] = *(const uint4*)&sm.O[lr * 128 + ((ch ^ (lr & 7)) << 3)];
                }
            }
        } else {
            if (tid < 128) {
                int lr = tid, rr = row0 + lr;
                if (rr < M) {
                    uint4* dst = (uint4*)&Db[(size_t)rr * N + col0];
                    #pragma unroll
                    for (int c = 0; c < 8; ++c)
                        dst[c] = *(const uint4*)&sm.O[lr * 128 + ((c ^ (lr & 7)) << 3)];
                }
            }
        }
    }
}

// ---------------- merged KV+Q projection (BK=32), interleaved K|V output ----------------
__launch_bounds__(256)
__global__ void gemm_kvq768(const unsigned short* __restrict__ A,
                            const unsigned short* __restrict__ WALLl,
                            const float* __restrict__ bALLl,
                            unsigned short* __restrict__ KV,
                            unsigned short* __restrict__ QB)
{
    __shared__ union {
        unsigned short AB[4][4096];
        unsigned short O[16384];
    } sm;
    const int tid = threadIdx.x;
    int f = xcd_swz(blockIdx.x, 5664);
    int tt, bx, by;
    if (f < 2832) { tt = f / 1416; int r = f % 1416; by = r / 6; bx = r % 6; }
    else          { int g = f - 2832; tt = 2 + g / 944; int r = g % 944; by = r / 4; bx = r % 4; }
    const int row0 = by * 128, col0 = bx * 128;
    const int wid = tid >> 6, lane = tid & 63;
    const int wr = wid >> 1, wc = wid & 1;
    const int l16 = lane & 15, kg = lane >> 4;

    const unsigned short* Ab = A + (size_t)tt * SP;
    const unsigned short* BT = WALLl + (size_t)tt * 196608;
    const float* bias = bALLl + tt * 768;

    f32x4 acc[4][4];
    const f32x4 zero = {0.f, 0.f, 0.f, 0.f};
    #pragma unroll
    for (int i = 0; i < 4; ++i)
        #pragma unroll
        for (int j = 0; j < 4; ++j) acc[i][j] = zero;

    const int lrow = lane >> 2, lchk = lane & 3;
    const int gsw = (lchk ^ ((lrow >> 1) & 3)) * 8;
    const unsigned short* Ap0 = Ab + (size_t)(row0 + wid * 32 + lrow) * 256 + gsw;
    const unsigned short* Ap1 = Ab + (size_t)(row0 + wid * 32 + 16 + lrow) * 256 + gsw;
    const unsigned short* Bp0 = BT + (size_t)(col0 + wid * 32 + lrow) * 256 + gsw;
    const unsigned short* Bp1 = BT + (size_t)(col0 + wid * 32 + 16 + lrow) * 256 + gsw;
    const int ofs0 = wid * 1024, ofs1 = wid * 1024 + 512;
    const int rsw = ((l16 >> 1) & 3);
    int cur = 0;

    #define STAGE_K(c, k0) do { \
        gl_lds16(Ap0 + (k0), &sm.AB[c][ofs0]); \
        gl_lds16(Ap1 + (k0), &sm.AB[c][ofs1]); \
        gl_lds16(Bp0 + (k0), &sm.AB[2 + (c)][ofs0]); \
        gl_lds16(Bp1 + (k0), &sm.AB[2 + (c)][ofs1]); \
    } while (0)

    STAGE_K(0, 0);
    for (int s = 0; s < 8; ++s) {
        if (s + 1 < 8) {
            STAGE_K(cur ^ 1, (s + 1) * 32);
            asm volatile("s_waitcnt vmcnt(4)" ::: "memory");
        } else {
            asm volatile("s_waitcnt vmcnt(0)" ::: "memory");
        }
        __builtin_amdgcn_s_barrier();
        asm volatile("" ::: "memory");
        short8 af[4], bfr[4];
        #pragma unroll
        for (int i = 0; i < 4; ++i) {
            af[i]  = *(const short8*)&sm.AB[cur][(wr * 64 + i * 16 + l16) * 32 + (kg ^ rsw) * 8];
            bfr[i] = *(const short8*)&sm.AB[2 + cur][(wc * 64 + i * 16 + l16) * 32 + (kg ^ rsw) * 8];
        }
        __builtin_amdgcn_s_setprio(1);
        #pragma unroll
        for (int i = 0; i < 4; ++i)
            #pragma unroll
            for (int j = 0; j < 4; ++j)
                acc[i][j] = __builtin_amdgcn_mfma_f32_16x16x32_bf16(af[i], bfr[j], acc[i][j], 0, 0, 0);
        __builtin_amdgcn_s_setprio(0);
        __builtin_amdgcn_s_barrier();
        asm volatile("" ::: "memory");
        cur ^= 1;
    }
    #undef STAGE_K

    #pragma unroll
    for (int j = 0; j < 4; ++j) {
        int lc = wc * 64 + j * 16 + l16;
        float bv = bias[col0 + lc];
        #pragma unroll
        for (int i = 0; i < 4; ++i) {
            #pragma unroll
            for (int r = 0; r < 4; ++r) {
                int lr = wr * 64 + i * 16 + kg * 4 + r;
                float v = acc[i][j][r] + bv;
                sm.O[lr * 128 + ((((lc >> 3) ^ (lr & 7)) << 3) | (lc & 7))] = f2bf(v);
            }
        }
    }
    __syncthreads();
    {
        int dsel = bx >> 1;
        unsigned short* T; int ldT, cofs;
        if (dsel == 2) { T = QB + (size_t)tt * SP;  ldT = 256; cofs = (bx & 1) * 128; }
        else           { T = KV + (size_t)tt * SP2; ldT = 512; cofs = dsel * 256 + (bx & 1) * 128; }
        int lr = tid >> 1, half = tid & 1;
        int rr = row0 + lr;
        uint4* dst = (uint4*)&T[(size_t)rr * ldT + cofs + half * 64];
        #pragma unroll
        for (int c = 0; c < 8; ++c) {
            int ch = half * 8 + c;
            dst[c] = *(const uint4*)&sm.O[lr * 128 + ((ch ^ (lr & 7)) << 3)];
        }
    }
}

// 2-segment out-projection: seg0=USER, seg1=ITEM; bf16 resid in, bf16 pre-BN out
__launch_bounds__(256)
__global__ void gemm_outproj(const unsigned short* __restrict__ A,
                             const unsigned short* __restrict__ BT0,
                             const float* __restrict__ bias0,
                             const float* __restrict__ skipB,
                             const unsigned short* __restrict__ XBres,
                             unsigned short* __restrict__ Db, float* __restrict__ bns)
{
    __shared__ unsigned short AB[4][4096];
    const int tid = threadIdx.x;
    int bid = xcd_swz(blockIdx.y * 2 + blockIdx.x, 2 * gridDim.y);
    const int bx = bid % 2, by = bid / 2;
    const int tt = by / 236;
    const int row0 = by * 128, col0 = bx * 128;
    const int row0l = row0 - tt * MPD;
    const int wid = tid >> 6, lane = tid & 63;
    const int wr = wid >> 1, wc = wid & 1;
    const int l16 = lane & 15, kg = lane >> 4;

    const unsigned short* BT = BT0 + (size_t)tt * 65536;
    const float* bias = bias0 + tt * 256;
    const unsigned short* resid = XBres + (size_t)tt * SP;
    unsigned short* Dp = Db + (size_t)tt * SP;
    float* bnp = bns + tt * 512;

    f32x4 acc[4][4];
    const f32x4 zero = {0.f, 0.f, 0.f, 0.f};
    #pragma unroll
    for (int i = 0; i < 4; ++i)
        #pragma unroll
        for (int j = 0; j < 4; ++j) acc[i][j] = zero;

    const int lrow = lane >> 2, lchk = lane & 3;
    const int gsw = (lchk ^ ((lrow >> 1) & 3)) * 8;
    int ar0 = min(row0l + wid * 32 + lrow, NNODE - 1);
    int ar1 = min(row0l + wid * 32 + 16 + lrow, NNODE - 1);
    const unsigned short* Ap0 = A + (size_t)tt * S + (size_t)ar0 * 256 + gsw;
    const unsigned short* Ap1 = A + (size_t)tt * S + (size_t)ar1 * 256 + gsw;
    const unsigned short* Bp0 = BT + (size_t)(col0 + wid * 32 + lrow) * 256 + gsw;
    const unsigned short* Bp1 = BT + (size_t)(col0 + wid * 32 + 16 + lrow) * 256 + gsw;
    const int ofs0 = wid * 1024, ofs1 = wid * 1024 + 512;
    const int rsw = ((l16 >> 1) & 3);
    int cur = 0;

    #define STAGE_O(c, k0) do { \
        gl_lds16(Ap0 + (k0), &AB[c][ofs0]); \
        gl_lds16(Ap1 + (k0), &AB[c][ofs1]); \
        gl_lds16(Bp0 + (k0), &AB[2 + (c)][ofs0]); \
        gl_lds16(Bp1 + (k0), &AB[2 + (c)][ofs1]); \
    } while (0)

    STAGE_O(0, 0);
    for (int s = 0; s < 8; ++s) {
        if (s + 1 < 8) {
            STAGE_O(cur ^ 1, (s + 1) * 32);
            asm volatile("s_waitcnt vmcnt(4)" ::: "memory");
        } else {
            asm volatile("s_waitcnt vmcnt(0)" ::: "memory");
        }
        __builtin_amdgcn_s_barrier();
        asm volatile("" ::: "memory");
        short8 af[4], bfr[4];
        #pragma unroll
        for (int i = 0; i < 4; ++i) {
            af[i]  = *(const short8*)&AB[cur][(wr * 64 + i * 16 + l16) * 32 + (kg ^ rsw) * 8];
            bfr[i] = *(const short8*)&AB[2 + cur][(wc * 64 + i * 16 + l16) * 32 + (kg ^ rsw) * 8];
        }
        __builtin_amdgcn_s_setprio(1);
        #pragma unroll
        for (int i = 0; i < 4; ++i)
            #pragma unroll
            for (int j = 0; j < 4; ++j)
                acc[i][j] = __builtin_amdgcn_mfma_f32_16x16x32_bf16(af[i], bfr[j], acc[i][j], 0, 0, 0);
        __builtin_amdgcn_s_setprio(0);
        __builtin_amdgcn_s_barrier();
        asm volatile("" ::: "memory");
        cur ^= 1;
    }
    #undef STAGE_O

    float sg = 1.f / (1.f + __expf(-skipB[tt]));
    #pragma unroll
    for (int j = 0; j < 4; ++j) {
        int cc = col0 + wc * 64 + j * 16 + l16;
        float cs = 0.f, cs2 = 0.f;
        float bv = bias[cc];
        #pragma unroll
        for (int i = 0; i < 4; ++i) {
            #pragma unroll
            for (int r = 0; r < 4; ++r) {
                int lr = row0l + wr * 64 + i * 16 + kg * 4 + r;
                if (lr < NNODE) {
                    float v = acc[i][j][r] + bv;
                    float xo = b2f(resid[(size_t)lr * 256 + cc]);
                    float o = sg * v + (2.f - sg) * xo;
                    Dp[(size_t)lr * 256 + cc] = f2bf(o);
                    cs += o; cs2 += o * o;
                }
            }
        }
        cs  += __shfl_xor(cs, 16);  cs  += __shfl_xor(cs, 32);
        cs2 += __shfl_xor(cs2, 16); cs2 += __shfl_xor(cs2, 32);
        if (kg == 0) {
            atomicAdd(&bnp[cc], cs);
            atomicAdd(&bnp[256 + cc], cs2);
        }
    }
}

// ------------- CSR build -------------
__global__ void edge_hist2(const int* __restrict__ dstk, const int* __restrict__ srck,
                           int* __restrict__ cnt)
{
    int j = blockIdx.x * 256 + threadIdx.x;
    if (j < EBUY) atomicAdd(&cnt[dstk[j]], 1);
    else if (j < 2 * EBUY) atomicAdd(&cnt[NNODE + srck[j - EBUY]], 1);
}

#define SCAN_NB 30
#define SCAN_CH 1000
__global__ void scan_part(const int* __restrict__ cnt, int* __restrict__ bt)
{
    int set = blockIdx.y;
    const int* c = cnt + set * NNODE;
    int b = blockIdx.x;
    int i = b * SCAN_CH + threadIdx.x;
    int v = (threadIdx.x < SCAN_CH && i < NNODE) ? c[i] : 0;
    __shared__ int wsum[16];
    int lane = threadIdx.x & 63, wv = threadIdx.x >> 6;
    for (int o = 32; o; o >>= 1) v += __shfl_down(v, o);
    if (lane == 0) wsum[wv] = v;
    __syncthreads();
    if (threadIdx.x == 0) {
        int s = 0;
        for (int w = 0; w < 16; ++w) s += wsum[w];
        bt[set * 32 + b] = s;
    }
}

__global__ void scan_mid(int* __restrict__ bt, int* __restrict__ off_i, int* __restrict__ off_u)
{
    int set = threadIdx.x;
    if (set >= 2) return;
    int* b = bt + set * 32;
    int s = 0;
    for (int i = 0; i < SCAN_NB; ++i) { int c = b[i]; b[i] = s; s += c; }
    (set ? off_u : off_i)[NNODE] = s;
}

__global__ void scan_final(const int* __restrict__ cnt, const int* __restrict__ bt,
                           int* __restrict__ off_i, int* __restrict__ off_u,
                           int* __restrict__ cur_i, int* __restrict__ cur_u)
{
    int set = blockIdx.y;
    const int* c = cnt + set * NNODE;
    int* off = set ? off_u : off_i;
    int* cur = set ? cur_u : cur_i;
    int b = blockIdx.x;
    int i = b * SCAN_CH + threadIdx.x;
    int v = (threadIdx.x < SCAN_CH && i < NNODE) ? c[i] : 0;
    int lane = threadIdx.x & 63, wv = threadIdx.x >> 6;
    int x = v;
    for (int o = 1; o < 64; o <<= 1) { int t = __shfl_up(x, o); if (lane >= o) x += t; }
    __shared__ int wtot[16];
    if (lane == 63) wtot[wv] = x;
    __syncthreads();
    if (wv == 0) {
        int y = (lane < 16) ? wtot[lane] : 0;
        for (int o = 1; o < 16; o <<= 1) { int t = __shfl_up(y, o); if (lane >= o) y += t; }
        if (lane < 16) wtot[lane] = y;
    }
    __syncthreads();
    int wbase = (wv == 0) ? 0 : wtot[wv - 1];
    int excl = bt[set * 32 + b] + wbase + x - v;
    if (threadIdx.x < SCAN_CH && i < NNODE) { off[i] = excl; cur[i] = excl; }
}

__global__ void edge_place2(const int* __restrict__ dstk, const int* __restrict__ srck,
                            int* __restrict__ cur_i, int* __restrict__ cur_u,
                            int* __restrict__ src_i, int* __restrict__ src_u)
{
    int j = blockIdx.x * 256 + threadIdx.x;
    if (j < EBUY) {
        int pos = atomicAdd(&cur_i[dstk[j]], 1);
        src_i[pos] = srck[j];
    } else if (j < 2 * EBUY) {
        int j2 = j - EBUY;
        int pos = atomicAdd(&cur_u[srck[j2]], 1);
        src_u[pos] = dstk[j2];
    }
}

// both attention sides; user -> AGB seg0, item -> AGB seg1; interleaved KV rows; depth-2 prefetch
__launch_bounds__(256)
__global__ void attn_both(const unsigned short* __restrict__ QB,
                          const unsigned short* __restrict__ KV,
                          const int* __restrict__ off_i, const int* __restrict__ src_i,
                          const int* __restrict__ off_u, const int* __restrict__ src_u,
                          const float* __restrict__ pR,
                          unsigned short* __restrict__ AGB)
{
    int gw = (blockIdx.x * 256 + threadIdx.x) >> 6;
    int lane = threadIdx.x & 63;
    if (gw >= 2 * NNODE) return;
    int h = lane >> 4;
    const bool item = gw < NNODE;
    const int wid = item ? gw : gw - NNODE;
    const unsigned short* Qd  = item ? QB + SP : QB;
    const unsigned short* KVs = item ? KV : KV + SP2;
    const int* roff = item ? off_i : off_u;
    const int* srcA = item ? src_i : src_u;
    unsigned short* outp = AGB + (item ? S : 0);

    ushort4 qb = *(const ushort4*)(Qd + (size_t)wid * 256 + lane * 4);
    float4 q = {b2f(qb.x), b2f(qb.y), b2f(qb.z), b2f(qb.w)};
    float m = -INFINITY, s = 0.f;
    float4 acc = {0.f, 0.f, 0.f, 0.f};

    #define AT_STEP(KBV, VBV, PSCALE) do { \
        float d = q.x * b2f((KBV).x) + q.y * b2f((KBV).y) + q.z * b2f((KBV).z) + q.w * b2f((KBV).w); \
        for (int off = 8; off; off >>= 1) d += __shfl_xor(d, off, 16); \
        float lg = d * (PSCALE); \
        float mn = fmaxf(m, lg); \
        float so = __expf(m - mn); \
        float ev = __expf(lg - mn); \
        s = s * so + ev; \
        acc.x = acc.x * so + ev * b2f((VBV).x); \
        acc.y = acc.y * so + ev * b2f((VBV).y); \
        acc.z = acc.z * so + ev * b2f((VBV).z); \
        acc.w = acc.w * so + ev * b2f((VBV).w); \
        m = mn; \
    } while (0)

    if (item) {
        #pragma unroll
        for (int e = 0; e < 3; ++e) {
            const unsigned short* kvrow = KV + (size_t)(2 + e) * SP2 + (size_t)wid * 512;
            ushort4 kb = *(const ushort4*)(kvrow + lane * 4);
            ushort4 vv = *(const ushort4*)(kvrow + 256 + lane * 4);
            AT_STEP(kb, vv, pR[e * 4 + h] * 0.125f);
        }
    }

    float pb = pR[(item ? 12 : 16) + h] * 0.125f;
    int j0 = roff[wid], j1 = roff[wid + 1];
    ushort4 kA = {0,0,0,0}, vA = {0,0,0,0}, kB = {0,0,0,0}, vB = {0,0,0,0};
    if (j0 < j1) {
        const unsigned short* r0 = KVs + (size_t)srcA[j0] * 512;
        kA = *(const ushort4*)(r0 + lane * 4);
        vA = *(const ushort4*)(r0 + 256 + lane * 4);
    }
    if (j0 + 1 < j1) {
        const unsigned short* r1 = KVs + (size_t)srcA[j0 + 1] * 512;
        kB = *(const ushort4*)(r1 + lane * 4);
        vB = *(const ushort4*)(r1 + 256 + lane * 4);
    }
    int j = j0;
    while (j < j1) {
        ushort4 ck = kA, cv = vA;
        if (j + 2 < j1) {
            const unsigned short* rn = KVs + (size_t)srcA[j + 2] * 512;
            kA = *(const ushort4*)(rn + lane * 4);
            vA = *(const ushort4*)(rn + 256 + lane * 4);
        }
        AT_STEP(ck, cv, pb);
        ++j;
        if (j >= j1) break;
        ck = kB; cv = vB;
        if (j + 2 < j1) {
            const unsigned short* rn = KVs + (size_t)srcA[j + 2] * 512;
            kB = *(const ushort4*)(rn + lane * 4);
            vB = *(const ushort4*)(rn + 256 + lane * 4);
        }
        AT_STEP(ck, cv, pb);
        ++j;
    }
    #undef AT_STEP

    float inv = 1.f / (s + 1e-16f);
    ushort4 o4;
    o4.x = f2bf(gelu_f(acc.x * inv));
    o4.y = f2bf(gelu_f(acc.y * inv));
    o4.z = f2bf(gelu_f(acc.z * inv));
    o4.w = f2bf(gelu_f(acc.w * inv));
    *(ushort4*)(outp + (size_t)wid * 256 + lane * 4) = o4;
}

// ------------- batch-norm -------------
#define BNB 512
__global__ void bn_stats2(const float* __restrict__ SCRf, float* __restrict__ part)
{
    int tt = blockIdx.y;
    const float* x = SCRf + (size_t)tt * SP;
    int col = threadIdx.x;
    int b = blockIdx.x;
    float s = 0.f, s2 = 0.f;
    int r = b;
    for (; r + 3 * BNB < NNODE; r += 4 * BNB) {
        float v0 = x[(size_t)r * 256 + col];
        float v1 = x[(size_t)(r + BNB) * 256 + col];
        float v2 = x[(size_t)(r + 2 * BNB) * 256 + col];
        float v3 = x[(size_t)(r + 3 * BNB) * 256 + col];
        s += v0 + v1 + v2 + v3;
        s2 += v0 * v0 + v1 * v1 + v2 * v2 + v3 * v3;
    }
    for (; r < NNODE; r += BNB) {
        float v = x[(size_t)r * 256 + col];
        s += v; s2 += v * v;
    }
    part[((size_t)tt * BNB + b) * 512 + col] = s;
    part[((size_t)tt * BNB + b) * 512 + 256 + col] = s2;
}

__global__ void bn_fin2(const float* __restrict__ part,
                        const float* __restrict__ g0, const float* __restrict__ b0,
                        const float* __restrict__ g1, const float* __restrict__ b1,
                        float* __restrict__ scsh)
{
    int tid = threadIdx.x;
    int tt = tid >> 8, col = tid & 255;
    const float* p = part + (size_t)tt * BNB * 512;
    float s = 0.f, s2 = 0.f;
    #pragma unroll 4
    for (int b = 0; b < BNB; ++b) { s += p[b * 512 + col]; s2 += p[b * 512 + 256 + col]; }
    float mu = s / (float)NNODE;
    float var = s2 / (float)NNODE - mu * mu;
    float sc = rsqrtf(var + 1e-5f) * (tt ? g1 : g0)[col];
    scsh[tt * 512 + col] = sc;
    scsh[tt * 512 + 256 + col] = (tt ? b1 : b0)[col] - mu * sc;
}

__global__ void bn_find2(const float* __restrict__ bns,
                         const float* __restrict__ g01, const float* __restrict__ b01,
                         float* __restrict__ scsh)
{
    int tid = threadIdx.x;
    int tt = tid >> 8, col = tid & 255;
    float s = bns[tt * 512 + col], s2 = bns[tt * 512 + 256 + col];
    float mu = s / (float)NNODE;
    float var = s2 / (float)NNODE - mu * mu;
    float sc = rsqrtf(var + 1e-5f) * g01[tt * 256 + col];
    scsh[tt * 512 + col] = sc;
    scsh[tt * 512 + 256 + col] = b01[tt * 256 + col] - mu * sc;
}

// f32-input apply (encoder path)
template<int WF32>
__global__ void bn_apply2(const float* __restrict__ SCRf, const float* __restrict__ scsh,
                          float* __restrict__ out, unsigned short* __restrict__ XBall)
{
    const int Q4 = NNODE * 64;
    for (int i = blockIdx.x * 256 + threadIdx.x; i < 2 * Q4; i += gridDim.x * 256) {
        int tt = (i >= Q4) ? 1 : 0;
        int local = i - tt * Q4;
        int c4 = local & 63;
        float4 sc4 = *(const float4*)&scsh[tt * 512 + c4 * 4];
        float4 sh4 = *(const float4*)&scsh[tt * 512 + 256 + c4 * 4];
        float4 v = ((const float4*)(SCRf + (size_t)tt * SP))[local];
        v.x = fmaxf(v.x * sc4.x + sh4.x, 0.f);
        v.y = fmaxf(v.y * sc4.y + sh4.y, 0.f);
        v.z = fmaxf(v.z * sc4.z + sh4.z, 0.f);
        v.w = fmaxf(v.w * sc4.w + sh4.w, 0.f);
        if (WF32) ((float4*)(out + (size_t)tt * S))[local] = v;
        ushort4 u = {f2bf(v.x), f2bf(v.y), f2bf(v.z), f2bf(v.w)};
        ((ushort4*)(XBall + (size_t)tt * SP))[local] = u;
    }
}

// bf16-input apply (layer path)
template<int WF32>
__global__ void bn_apply2b(const unsigned short* __restrict__ SCRb, const float* __restrict__ scsh,
                           float* __restrict__ out, unsigned short* __restrict__ XBall)
{
    const int Q4 = NNODE * 64;
    for (int i = blockIdx.x * 256 + threadIdx.x; i < 2 * Q4; i += gridDim.x * 256) {
        int tt = (i >= Q4) ? 1 : 0;
        int local = i - tt * Q4;
        int c4 = local & 63;
        float4 sc4 = *(const float4*)&scsh[tt * 512 + c4 * 4];
        float4 sh4 = *(const float4*)&scsh[tt * 512 + 256 + c4 * 4];
        ushort4 b4 = ((const ushort4*)(SCRb + (size_t)tt * SP))[local];
        float4 v = {b2f(b4.x), b2f(b4.y), b2f(b4.z), b2f(b4.w)};
        v.x = fmaxf(v.x * sc4.x + sh4.x, 0.f);
        v.y = fmaxf(v.y * sc4.y + sh4.y, 0.f);
        v.z = fmaxf(v.z * sc4.z + sh4.z, 0.f);
        v.w = fmaxf(v.w * sc4.w + sh4.w, 0.f);
        if (WF32) ((float4*)(out + (size_t)tt * S))[local] = v;
        ushort4 u = {f2bf(v.x), f2bf(v.y), f2bf(v.z), f2bf(v.w)};
        ((ushort4*)(XBall + (size_t)tt * SP))[local] = u;
    }
}

extern "C" void kernel_launch(void* const* d_in, const int* in_sizes, int n_in,
                              void* d_out, int out_size, void* d_ws, size_t ws_size,
                              hipStream_t stream)
{
    const int*   user_id    = (const int*)d_in[0];
    const int*   item_id    = (const int*)d_in[1];
    const int*   buys_src   = (const int*)d_in[2];
    const int*   buys_dst   = (const int*)d_in[3];
    const float* image_feat = (const float*)d_in[4];
    const float* taste_feat = (const float*)d_in[5];
    const float* intent_feat= (const float*)d_in[6];
    const float* user_emb   = (const float*)d_in[7];
    const float* user_W     = (const float*)d_in[8];
    const float* user_b     = (const float*)d_in[9];
    const float* user_bn_g  = (const float*)d_in[10];
    const float* user_bn_b  = (const float*)d_in[11];
    const float* item_emb   = (const float*)d_in[12];
    const float* item_W     = (const float*)d_in[13];
    const float* item_b     = (const float*)d_in[14];
    const float* item_bn_g  = (const float*)d_in[15];
    const float* item_bn_b  = (const float*)d_in[16];
    const float* img_U      = (const float*)d_in[17];
    const float* img_V      = (const float*)d_in[18];
    const float* img_b      = (const float*)d_in[19];
    const float* taste_W    = (const float*)d_in[20];
    const float* taste_b    = (const float*)d_in[21];
    const float* intent_W   = (const float*)d_in[22];
    const float* intent_b   = (const float*)d_in[23];
    const float* kqv_W      = (const float*)d_in[24];
    const float* kqv_b      = (const float*)d_in[25];
    const float* out_W      = (const float*)d_in[26];
    const float* out_b      = (const float*)d_in[27];
    const float* k_rel      = (const float*)d_in[28];
    const float* v_rel      = (const float*)d_in[29];
    const float* p_rel      = (const float*)d_in[30];
    const float* skip       = (const float*)d_in[31];
    const float* fbn_g      = (const float*)d_in[32];
    const float* fbn_b      = (const float*)d_in[33];

    float* out = (float*)d_out;
    float* ws  = (float*)d_ws;

    float* SCRf = ws;
    float* BNSp = SCRf + 2 * SP;
    float* BNS  = BNSp + 2 * BNB * 512;
    float* SCSH = BNS + 1024;
    float* bALL = SCSH + 1024;
    unsigned short* QB    = (unsigned short*)(bALL + 7680);
    unsigned short* XBall = QB + 2 * SP;
    unsigned short* KVall = XBall + 5 * SP;
    unsigned short* AGB   = KVall + 5 * SP2;
    unsigned short* IMB   = AGB + 2 * S;
    unsigned short* IPB   = IMB + (size_t)NNODE * 64;
    unsigned short* WALL  = IPB + (size_t)NNODE * 32;
    unsigned short* WENC  = WALL + (size_t)10 * 196608;
    int* cnt   = (int*)(WENC + WENC_TOT);
    int* off_i = cnt + 2 * NNODE;
    int* off_u = off_i + NNODE + 1;
    int* cur_i = off_u + NNODE + 1;
    int* cur_u = cur_i + NNODE;
    int* src_i = cur_u + NNODE;
    int* src_u = src_i + EBUY;
    int* bt    = src_u + EBUY;

    size_t need = (size_t)((char*)(bt + 64) - (char*)ws);
    if (ws_size < need) return;

    unsigned short* TFB  = (unsigned short*)SCRf;   // encoder-phase aliases (consumed before overwrite)
    unsigned short* IFB  = QB;
    unsigned short* SCRb = (unsigned short*)SCRf;   // layer-phase bf16 pre-BN scratch

    hipMemsetAsync(cnt, 0, 2 * NNODE * 4, stream);
    edge_hist2<<<(2 * EBUY + 255) / 256, 256, 0, stream>>>(buys_dst, buys_src, cnt);
    scan_part<<<dim3(SCAN_NB, 2), 1024, 0, stream>>>(cnt, bt);
    scan_mid<<<1, 64, 0, stream>>>(bt, off_i, off_u);
    scan_final<<<dim3(SCAN_NB, 2), 1024, 0, stream>>>(cnt, bt, off_i, off_u, cur_i, cur_u);
    edge_place2<<<(2 * EBUY + 255) / 256, 256, 0, stream>>>(buys_dst, buys_src, cur_i, cur_u, src_i, src_u);

    wtconv_all<<<(WENC_TOT + 255) / 256, 256, 0, stream>>>(taste_W, intent_W, img_U, img_V,
                                                           user_W, item_W, out_W, WENC);
    build_kqv<<<dim3(771, 10), 256, 0, stream>>>(kqv_W, kqv_b, k_rel, v_rel, WALL, bALL);
    conv_pad<<<(NNODE * 32 + 255) / 256, 256, 0, stream>>>(intent_feat, IPB, NNODE, 20, 32);
    conv2bf<<<2048, 256, 0, stream>>>(taste_feat, 5760000, TFB, image_feat, 3840000, IFB);

    hipLaunchKernelGGL((gemm_mfma<0,0,0>), dim3(2,235), dim3(256), 0, stream,
        TFB, nullptr, nullptr, nullptr, WENC + OFF_TASTE, taste_b, nullptr,
        out + 2*S, XBall + 2*SP, NNODE, 256, 768);
    hipLaunchKernelGGL((gemm_mfma<0,0,0>), dim3(2,235), dim3(256), 0, stream,
        IPB, nullptr, nullptr, nullptr, WENC + OFF_INT, intent_b, nullptr,
        out + 3*S, XBall + 3*SP, NNODE, 256, 32);
    hipLaunchKernelGGL((gemm_mfma<0,0,0>), dim3(1,235), dim3(256), 0, stream,
        IFB, nullptr, nullptr, nullptr, WENC + OFF_IMGU, nullptr, nullptr,
        nullptr, IMB, NNODE, 64, 512);
    hipLaunchKernelGGL((gemm_mfma<0,0,0>), dim3(2,235), dim3(256), 0, stream,
        IMB, nullptr, nullptr, nullptr, WENC + OFF_IMGV, img_b, nullptr,
        out + 4*S, XBall + 4*SP, NNODE, 256, 64);
    hipLaunchKernelGGL((gemm_mfma<1,1,6>), dim3(2,472), dim3(256), 0, stream,
        user_emb, item_emb, user_id, item_id, WENC + OFF_USER, user_b, item_b,
        SCRf, nullptr, 2*MPD, 256, 64);
    bn_stats2<<<dim3(BNB, 2), 256, 0, stream>>>(SCRf, BNSp);
    bn_fin2<<<1, 512, 0, stream>>>(BNSp, user_bn_g, user_bn_b, item_bn_g, item_bn_b, SCSH);
    bn_apply2<0><<<960, 256, 0, stream>>>(SCRf, SCSH, out, XBall);

    for (int l = 0; l < 2; ++l) {
        hipLaunchKernelGGL(gemm_kvq768, dim3(5664), dim3(256), 0, stream,
            XBall, WALL + (size_t)l*5*196608, bALL + l*5*768, KVall, QB);
        hipLaunchKernelGGL(attn_both, dim3((2*NNODE*64 + 255)/256), dim3(256), 0, stream,
            QB, KVall, off_i, src_i, off_u, src_u, p_rel + l*20, AGB);
        hipMemsetAsync(BNS, 0, 1024 * 4, stream);
        hipLaunchKernelGGL(gemm_outproj, dim3(2, 472), dim3(256), 0, stream,
            AGB, WENC + OFF_OUTW + (size_t)l*2*65536, out_b + (size_t)l*5*256,
            skip + l*5, XBall, SCRb, BNS);
        bn_find2<<<1, 512, 0, stream>>>(BNS, fbn_g + (size_t)l*2*256, fbn_b + (size_t)l*2*256, SCSH);
        if (l == 0) bn_apply2b<0><<<960, 256, 0, stream>>>(SCRb, SCSH, out, XBall);
        else        bn_apply2b<1><<<960, 256, 0, stream>>>(SCRb, SCSH, out, XBall);
    }
}